// Round 1
// baseline (370.453 us; speedup 1.0000x reference)
//
#include <hip/hip_runtime.h>
#include <hip/hip_bf16.h>

#define S_ 8192
#define D_ 512
#define WSZ 512
#define QBLK 128
#define KBLK 64
#define NTHREADS 512
#define LDS_BYTES (65536 + 65536 + 8 * 2048)

using bf16x8 = __attribute__((ext_vector_type(8))) __bf16;
using f32x4  = __attribute__((ext_vector_type(4))) float;

__global__ __launch_bounds__(NTHREADS, 2) void gats_attn(
    const float* __restrict__ Qg, const float* __restrict__ Kg,
    const float* __restrict__ Vg, float* __restrict__ Og)
{
    extern __shared__ char smem[];
    char* Ksh = smem;               // K tile [64 keys][512 d] bf16, row stride 1024B, swizzled
    char* Vsh = smem + 65536;       // V tile transposed [512 d][64 keys] bf16, row stride 128B, swizzled
    const int tid  = threadIdx.x;
    const int lane = tid & 63;
    const int wv   = tid >> 6;
    char* Psh = smem + 131072 + wv * 2048;  // per-wave P [16 q][64 k] bf16, row stride 128B, swizzled

    const int bid = blockIdx.x;          // id = y*64 + b*16 + w  (same (b,w) -> same XCD)
    const int y   = bid >> 6;
    const int bw  = bid & 63;
    const int b   = bw >> 4;
    const int w   = bw & 15;
    const int qbase  = w * WSZ + y * QBLK;
    const int wqbase = qbase + wv * 16;

    const size_t boff = (size_t)b * S_ * D_;
    const float* Qp = Qg + boff;
    const float* Kp = Kg + boff;
    const float* Vp = Vg + boff;
    float*       Op = Og + boff;

    const float scale = 0.044194173824159216f;  // 1/sqrt(512)
    const float L2E   = 1.44269504088896f;

    // ---- Q fragments: 16 rows x 512, scaled, bf16, kept in registers ----
    bf16x8 qf[16];
    {
        const int qrow = wqbase + (lane & 15);
        const float* qsrc = Qp + (size_t)qrow * D_ + ((lane >> 4) * 8);
        #pragma unroll
        for (int c = 0; c < 16; ++c) {
            float4 a0 = *(const float4*)(qsrc + c * 32);
            float4 a1 = *(const float4*)(qsrc + c * 32 + 4);
            bf16x8 q;
            q[0] = (__bf16)(a0.x * scale); q[1] = (__bf16)(a0.y * scale);
            q[2] = (__bf16)(a0.z * scale); q[3] = (__bf16)(a0.w * scale);
            q[4] = (__bf16)(a1.x * scale); q[5] = (__bf16)(a1.y * scale);
            q[6] = (__bf16)(a1.z * scale); q[7] = (__bf16)(a1.w * scale);
            qf[c] = q;
        }
    }

    f32x4 acc[32];
    #pragma unroll
    for (int i = 0; i < 32; ++i) acc[i] = (f32x4){0.f, 0.f, 0.f, 0.f};
    float m_r[4], l_r[4];
    #pragma unroll
    for (int r = 0; r < 4; ++r) { m_r[r] = -1e30f; l_r[r] = 0.f; }

    const int kstart = (w == 0) ? 0 : (w - 1) * WSZ;
    const int ktend  = qbase + QBLK;

    for (int kt = kstart; kt < ktend; kt += KBLK) {
        __syncthreads();
        // ---- stage K [64][512] bf16, swizzled ----
        #pragma unroll
        for (int it = 0; it < 8; ++it) {
            const int row = it * 8 + wv;          // (it*512+tid)>>6
            const int d8  = (tid & 63) << 3;
            const float4* src = (const float4*)(Kp + (size_t)(kt + row) * D_ + d8);
            float4 a0 = src[0], a1 = src[1];
            bf16x8 kv;
            kv[0] = (__bf16)a0.x; kv[1] = (__bf16)a0.y; kv[2] = (__bf16)a0.z; kv[3] = (__bf16)a0.w;
            kv[4] = (__bf16)a1.x; kv[5] = (__bf16)a1.y; kv[6] = (__bf16)a1.z; kv[7] = (__bf16)a1.w;
            const int byte = row * 1024 + ((d8 << 1) ^ ((row & 7) << 4));
            *(bf16x8*)(Ksh + byte) = kv;
        }
        // ---- stage V transposed: Vt[d][key], coalesced global reads ----
        {
            const int d = tid;  // 0..511
            #pragma unroll
            for (int it = 0; it < 8; ++it) {
                float vvv[8];
                #pragma unroll
                for (int j = 0; j < 8; ++j)
                    vvv[j] = Vp[(size_t)(kt + it * 8 + j) * D_ + d];
                bf16x8 vb;
                #pragma unroll
                for (int j = 0; j < 8; ++j) vb[j] = (__bf16)vvv[j];
                const int byte = d * 128 + ((it * 16) ^ ((d & 7) << 4));
                *(bf16x8*)(Vsh + byte) = vb;
            }
        }
        __syncthreads();

        if (kt > wqbase + 15) continue;  // wave fully above causal diagonal for this tile

        // ---- S = Q K^T : [16 q][64 keys] in 4 groups of 16 ----
        f32x4 sacc[4];
        #pragma unroll
        for (int g = 0; g < 4; ++g) {
            f32x4 s = (f32x4){0.f, 0.f, 0.f, 0.f};
            const int keyrow = g * 16 + (lane & 15);
            #pragma unroll
            for (int c = 0; c < 16; ++c) {
                const int byte = keyrow * 1024 +
                                 ((c * 64 + (lane >> 4) * 16) ^ ((keyrow & 7) << 4));
                bf16x8 kf = *(const bf16x8*)(Ksh + byte);
                s = __builtin_amdgcn_mfma_f32_16x16x32_bf16(qf[c], kf, s, 0, 0, 0);
            }
            sacc[g] = s;
        }

        // ---- causal mask (key > query) ----
        #pragma unroll
        for (int g = 0; g < 4; ++g) {
            if (kt + g * 16 + 15 > wqbase) {      // group touches/passes diagonal
                const int kg = kt + g * 16 + (lane & 15);
                #pragma unroll
                for (int r = 0; r < 4; ++r) {
                    const int qrow = wqbase + (lane >> 4) * 4 + r;
                    if (kg > qrow) sacc[g][r] = -1e30f;
                }
            }
        }

        // ---- tile row max (reduce over the 16 lanes of each row group) ----
        float tmax[4];
        #pragma unroll
        for (int r = 0; r < 4; ++r) {
            float v = fmaxf(fmaxf(sacc[0][r], sacc[1][r]), fmaxf(sacc[2][r], sacc[3][r]));
            #pragma unroll
            for (int off = 8; off >= 1; off >>= 1)
                v = fmaxf(v, __shfl_xor(v, off));
            tmax[r] = v;
        }

        // ---- deferred-max online softmax rescale ----
        bool need = false;
        #pragma unroll
        for (int r = 0; r < 4; ++r) need |= (tmax[r] > m_r[r] + 8.f);
        if (__any(need)) {
            #pragma unroll
            for (int r = 0; r < 4; ++r) {
                const float mnew = fmaxf(m_r[r], tmax[r]);
                const float f = exp2f((m_r[r] - mnew) * L2E);
                m_r[r] = mnew;
                l_r[r] *= f;
                #pragma unroll
                for (int dc = 0; dc < 32; ++dc) acc[dc][r] *= f;
            }
        }

        // ---- P = exp(S - m); write bf16 P to per-wave LDS; accumulate row sums ----
        float rsum[4] = {0.f, 0.f, 0.f, 0.f};
        #pragma unroll
        for (int g = 0; g < 4; ++g) {
            #pragma unroll
            for (int r = 0; r < 4; ++r) {
                const float p = exp2f((sacc[g][r] - m_r[r]) * L2E);
                rsum[r] += p;
                const int prow = (lane >> 4) * 4 + r;
                const int byte = prow * 128 +
                                 ((g * 32 + (lane & 15) * 2) ^ ((prow & 7) << 4));
                *(__bf16*)(Psh + byte) = (__bf16)p;
            }
        }
        #pragma unroll
        for (int r = 0; r < 4; ++r) {
            float v = rsum[r];
            #pragma unroll
            for (int off = 8; off >= 1; off >>= 1)
                v += __shfl_xor(v, off);
            l_r[r] += v;
        }

        // ---- O += P x V ----
        #pragma unroll
        for (int ks = 0; ks < 2; ++ks) {
            const int prow  = lane & 15;
            const int pbyte = prow * 128 +
                              ((ks * 64 + (lane >> 4) * 16) ^ ((prow & 7) << 4));
            bf16x8 pa = *(const bf16x8*)(Psh + pbyte);
            #pragma unroll
            for (int dc = 0; dc < 32; ++dc) {
                const int d = dc * 16 + (lane & 15);
                const int vbyte = d * 128 +
                                  ((ks * 64 + (lane >> 4) * 16) ^ ((d & 7) << 4));
                bf16x8 vf = *(const bf16x8*)(Vsh + vbyte);
                acc[dc] = __builtin_amdgcn_mfma_f32_16x16x32_bf16(pa, vf, acc[dc], 0, 0, 0);
            }
        }
    }

    // ---- epilogue: normalize and store ----
    float inv[4];
    #pragma unroll
    for (int r = 0; r < 4; ++r) inv[r] = 1.0f / l_r[r];
    #pragma unroll
    for (int dc = 0; dc < 32; ++dc) {
        #pragma unroll
        for (int r = 0; r < 4; ++r) {
            const int row = wqbase + (lane >> 4) * 4 + r;
            const int col = dc * 16 + (lane & 15);
            Op[(size_t)row * D_ + col] = acc[dc][r] * inv[r];
        }
    }
}

extern "C" void kernel_launch(void* const* d_in, const int* in_sizes, int n_in,
                              void* d_out, int out_size, void* d_ws, size_t ws_size,
                              hipStream_t stream) {
    const float* q = (const float*)d_in[0];   // text
    const float* k = (const float*)d_in[1];   // audio
    const float* v = (const float*)d_in[2];   // video
    float* o = (float*)d_out;
    hipFuncSetAttribute((const void*)gats_attn,
                        hipFuncAttributeMaxDynamicSharedMemorySize, LDS_BYTES);
    gats_attn<<<dim3(256), dim3(NTHREADS), LDS_BYTES, stream>>>(q, k, v, o);
}

// Round 2
// 359.668 us; speedup vs baseline: 1.0300x; 1.0300x over previous
//
#include <hip/hip_runtime.h>
#include <hip/hip_bf16.h>

#define S_ 8192
#define D_ 512
#define WSZ 512
#define QBLK 64
#define KBLK 32
#define NTHREADS 256
// K: 32x512 bf16 = 32KB, Vt: 512x32 bf16 = 32KB, P: 4 waves x 1KB = 4KB
#define LDS_BYTES (32768 + 32768 + 4 * 1024)

using bf16x8 = __attribute__((ext_vector_type(8))) __bf16;
using f32x4  = __attribute__((ext_vector_type(4))) float;

__global__ __launch_bounds__(NTHREADS, 2) void gats_attn(
    const float* __restrict__ Qg, const float* __restrict__ Kg,
    const float* __restrict__ Vg, float* __restrict__ Og)
{
    extern __shared__ char smem[];
    char* Ksh = smem;                 // [32 keys][512 d] bf16, row stride 1024B, swz ^((row&7)<<4)
    char* Vsh = smem + 32768;         // Vt [512 d][32 keys] bf16, row stride 64B, swz ^(((d>>1)&3)<<4)
    const int tid  = threadIdx.x;
    const int lane = tid & 63;
    const int wv   = tid >> 6;        // 4 waves
    char* Psh = smem + 65536 + wv * 1024;  // per-wave P [16 q][32 k] bf16, row stride 64B

    // bid layout: low 3 bits = w>>1 (XCD id), then w&1, b(2), y(3).
    // -> all y-blocks of (b,w) and the paired window share an XCD L2;
    //    co-resident pair (bid, bid+256) shares the same (b,w) K/V stream.
    const int bid = blockIdx.x;
    const int wh  = bid & 7;
    const int r2  = bid >> 3;
    const int w   = wh * 2 + (r2 & 1);
    const int b   = (r2 >> 1) & 3;
    const int y   = r2 >> 3;                 // 0..7
    const int qbase  = w * WSZ + y * QBLK;
    const int wqbase = qbase + wv * 16;

    const size_t boff = (size_t)b * S_ * D_;
    const float* Qp = Qg + boff;
    const float* Kp = Kg + boff;
    const float* Vp = Vg + boff;
    float*       Op = Og + boff;

    const float scale = 0.044194173824159216f;  // 1/sqrt(512)
    const float L2E   = 1.44269504088896f;

    // ---- Q fragments: 16 rows x 512 d, scaled, bf16, in registers (64 VGPR) ----
    bf16x8 qf[16];
    {
        const int qrow = wqbase + (lane & 15);
        const float* qsrc = Qp + (size_t)qrow * D_ + ((lane >> 4) * 8);
        #pragma unroll
        for (int c = 0; c < 16; ++c) {
            float4 a0 = *(const float4*)(qsrc + c * 32);
            float4 a1 = *(const float4*)(qsrc + c * 32 + 4);
            bf16x8 q;
            q[0] = (__bf16)(a0.x * scale); q[1] = (__bf16)(a0.y * scale);
            q[2] = (__bf16)(a0.z * scale); q[3] = (__bf16)(a0.w * scale);
            q[4] = (__bf16)(a1.x * scale); q[5] = (__bf16)(a1.y * scale);
            q[6] = (__bf16)(a1.z * scale); q[7] = (__bf16)(a1.w * scale);
            qf[c] = q;
        }
    }

    f32x4 acc[32];
    #pragma unroll
    for (int i = 0; i < 32; ++i) acc[i] = (f32x4){0.f, 0.f, 0.f, 0.f};
    float m_r[4], l_r[4];
    #pragma unroll
    for (int r = 0; r < 4; ++r) { m_r[r] = -1e30f; l_r[r] = 0.f; }

    const int kstart = (w == 0) ? 0 : (w - 1) * WSZ;
    const int ktend  = qbase + QBLK;

    for (int kt = kstart; kt < ktend; kt += KBLK) {
        __syncthreads();
        // ---- stage K [32][512] bf16, swizzled: 8 steps x (2 float4 -> 1 b128) ----
        #pragma unroll
        for (int s = 0; s < 8; ++s) {
            const int row = s * 4 + wv;
            const int dof = lane * 8;
            const float4* src = (const float4*)(Kp + (size_t)(kt + row) * D_ + dof);
            float4 a0 = src[0], a1 = src[1];
            bf16x8 kv;
            kv[0] = (__bf16)a0.x; kv[1] = (__bf16)a0.y; kv[2] = (__bf16)a0.z; kv[3] = (__bf16)a0.w;
            kv[4] = (__bf16)a1.x; kv[5] = (__bf16)a1.y; kv[6] = (__bf16)a1.z; kv[7] = (__bf16)a1.w;
            const int byte = row * 1024 + ((dof * 2) ^ ((row & 7) << 4));
            *(bf16x8*)(Ksh + byte) = kv;
        }
        // ---- stage V transposed: Vt[d][key]; thread owns d = tid, tid+256 ----
        #pragma unroll
        for (int h = 0; h < 2; ++h) {
            const int d = tid + h * 256;
            #pragma unroll
            for (int it = 0; it < 4; ++it) {
                float vvv[8];
                #pragma unroll
                for (int j = 0; j < 8; ++j)
                    vvv[j] = Vp[(size_t)(kt + it * 8 + j) * D_ + d];
                bf16x8 vb;
                #pragma unroll
                for (int j = 0; j < 8; ++j) vb[j] = (__bf16)vvv[j];
                const int byte = d * 64 + ((it * 16) ^ (((d >> 1) & 3) << 4));
                *(bf16x8*)(Vsh + byte) = vb;
            }
        }
        __syncthreads();

        if (kt > wqbase + 15) continue;  // wave fully above causal diagonal

        // ---- S = Q K^T : [16 q][32 keys] in 2 groups of 16 ----
        f32x4 sacc[2];
        #pragma unroll
        for (int g = 0; g < 2; ++g) {
            f32x4 s = (f32x4){0.f, 0.f, 0.f, 0.f};
            const int keyrow = g * 16 + (lane & 15);
            #pragma unroll
            for (int c = 0; c < 16; ++c) {
                const int byte = keyrow * 1024 +
                                 ((c * 64 + (lane >> 4) * 16) ^ ((keyrow & 7) << 4));
                bf16x8 kf = *(const bf16x8*)(Ksh + byte);
                s = __builtin_amdgcn_mfma_f32_16x16x32_bf16(qf[c], kf, s, 0, 0, 0);
            }
            sacc[g] = s;
        }

        // ---- causal mask ----
        #pragma unroll
        for (int g = 0; g < 2; ++g) {
            if (kt + g * 16 + 15 > wqbase) {
                const int kg = kt + g * 16 + (lane & 15);
                #pragma unroll
                for (int r = 0; r < 4; ++r) {
                    const int qrow = wqbase + (lane >> 4) * 4 + r;
                    if (kg > qrow) sacc[g][r] = -1e30f;
                }
            }
        }

        // ---- tile row max ----
        float tmax[4];
        #pragma unroll
        for (int r = 0; r < 4; ++r) {
            float v = fmaxf(sacc[0][r], sacc[1][r]);
            #pragma unroll
            for (int off = 8; off >= 1; off >>= 1)
                v = fmaxf(v, __shfl_xor(v, off));
            tmax[r] = v;
        }

        // ---- deferred-max online rescale ----
        bool need = false;
        #pragma unroll
        for (int r = 0; r < 4; ++r) need |= (tmax[r] > m_r[r] + 8.f);
        if (__any(need)) {
            #pragma unroll
            for (int r = 0; r < 4; ++r) {
                const float mnew = fmaxf(m_r[r], tmax[r]);
                const float f = exp2f((m_r[r] - mnew) * L2E);
                m_r[r] = mnew;
                l_r[r] *= f;
                #pragma unroll
                for (int dc = 0; dc < 32; ++dc) acc[dc][r] *= f;
            }
        }

        // ---- P = exp(S - m) -> bf16 LDS; row sums ----
        float rsum[4] = {0.f, 0.f, 0.f, 0.f};
        #pragma unroll
        for (int g = 0; g < 2; ++g) {
            #pragma unroll
            for (int r = 0; r < 4; ++r) {
                const float p = exp2f((sacc[g][r] - m_r[r]) * L2E);
                rsum[r] += p;
                const int prow = (lane >> 4) * 4 + r;
                const int byte = prow * 64 +
                                 ((g * 32 + (lane & 15) * 2) ^ (((prow >> 1) & 3) << 4));
                *(__bf16*)(Psh + byte) = (__bf16)p;
            }
        }
        #pragma unroll
        for (int r = 0; r < 4; ++r) {
            float v = rsum[r];
            #pragma unroll
            for (int off = 8; off >= 1; off >>= 1)
                v += __shfl_xor(v, off);
            l_r[r] += v;
        }

        // ---- O += P x V  (K=32 -> one mfma per 16-d chunk) ----
        {
            const int prow  = lane & 15;
            const int pbyte = prow * 64 +
                              (((lane >> 4) * 16) ^ (((prow >> 1) & 3) << 4));
            bf16x8 pa = *(const bf16x8*)(Psh + pbyte);
            #pragma unroll
            for (int dc = 0; dc < 32; ++dc) {
                const int d = dc * 16 + (lane & 15);
                const int vbyte = d * 64 +
                                  (((lane >> 4) * 16) ^ (((d >> 1) & 3) << 4));
                bf16x8 vf = *(const bf16x8*)(Vsh + vbyte);
                acc[dc] = __builtin_amdgcn_mfma_f32_16x16x32_bf16(pa, vf, acc[dc], 0, 0, 0);
            }
        }
    }

    // ---- epilogue: normalize and store ----
    float inv[4];
    #pragma unroll
    for (int r = 0; r < 4; ++r) inv[r] = 1.0f / l_r[r];
    #pragma unroll
    for (int dc = 0; dc < 32; ++dc) {
        #pragma unroll
        for (int r = 0; r < 4; ++r) {
            const int row = wqbase + (lane >> 4) * 4 + r;
            const int col = dc * 16 + (lane & 15);
            Op[(size_t)row * D_ + col] = acc[dc][r] * inv[r];
        }
    }
}

extern "C" void kernel_launch(void* const* d_in, const int* in_sizes, int n_in,
                              void* d_out, int out_size, void* d_ws, size_t ws_size,
                              hipStream_t stream) {
    const float* q = (const float*)d_in[0];   // text
    const float* k = (const float*)d_in[1];   // audio
    const float* v = (const float*)d_in[2];   // video
    float* o = (float*)d_out;
    hipFuncSetAttribute((const void*)gats_attn,
                        hipFuncAttributeMaxDynamicSharedMemorySize, LDS_BYTES);
    gats_attn<<<dim3(512), dim3(NTHREADS), LDS_BYTES, stream>>>(q, k, v, o);
}

// Round 3
// 271.639 us; speedup vs baseline: 1.3638x; 1.3241x over previous
//
#include <hip/hip_runtime.h>
#include <hip/hip_bf16.h>

#define S_ 8192
#define D_ 512
#define WSZ 512

using bf16x8 = __attribute__((ext_vector_type(8))) __bf16;
using f32x4  = __attribute__((ext_vector_type(4))) float;

#define GLDS(gp, lp) __builtin_amdgcn_global_load_lds( \
    (const __attribute__((address_space(1))) void*)(gp), \
    (__attribute__((address_space(3))) void*)(lp), 16, 0, 0)

// ---------------- pre-pass 1: K fp32 -> bf16 (layout unchanged) ----------------
__global__ __launch_bounds__(256) void cvt_k(const float* __restrict__ in,
                                             ushort* __restrict__ out) {
    const size_t i = ((size_t)blockIdx.x * 256 + threadIdx.x) * 8;
    float4 a0 = *(const float4*)(in + i);
    float4 a1 = *(const float4*)(in + i + 4);
    bf16x8 o;
    o[0] = (__bf16)a0.x; o[1] = (__bf16)a0.y; o[2] = (__bf16)a0.z; o[3] = (__bf16)a0.w;
    o[4] = (__bf16)a1.x; o[5] = (__bf16)a1.y; o[6] = (__bf16)a1.z; o[7] = (__bf16)a1.w;
    *(bf16x8*)(out + i) = o;
}

// ---------------- pre-pass 2: V fp32 [b][s][d] -> bf16 Vt [b][d][s] ----------------
__global__ __launch_bounds__(256) void tr_v(const float* __restrict__ V,
                                            ushort* __restrict__ Vt) {
    __shared__ float tile[64][68];
    const int bid = blockIdx.x;            // 4096 = 8 dblk x 128 sblk x 4 b
    const int d0 = (bid & 7) * 64;
    const int s0 = ((bid >> 3) & 127) * 64;
    const int b  = bid >> 10;
    const int t  = threadIdx.x;
    {
        const int sl = t >> 2, cg = (t & 3) * 16;
        const float* src = V + ((size_t)b * S_ + s0 + sl) * D_ + d0 + cg;
        #pragma unroll
        for (int j = 0; j < 4; ++j) {
            float4 a = *(const float4*)(src + j * 4);
            *(float4*)&tile[sl][cg + j * 4] = a;
        }
    }
    __syncthreads();
    {
        const int dl = t >> 2, sg = (t & 3) * 16;
        ushort* dst = Vt + ((size_t)b * D_ + d0 + dl) * S_ + s0 + sg;
        bf16x8 o0, o1;
        #pragma unroll
        for (int j = 0; j < 8; ++j) {
            o0[j] = (__bf16)tile[sg + j][dl];
            o1[j] = (__bf16)tile[sg + 8 + j][dl];
        }
        *(bf16x8*)(dst)     = o0;
        *(bf16x8*)(dst + 8) = o1;
    }
}

// ---------------- main attention: bf16 K/Vt in ws, global_load_lds double-buffer ----------------
#define QBLK 128
#define KBLK 32
#define ATT_THREADS 512
#define ATT_LDS (2 * 65536 + 8 * 1024)   // 2 x (K 32KB + Vt 32KB) + 8-wave P

__global__ __launch_bounds__(ATT_THREADS, 2) void gats_attn(
    const float* __restrict__ Qg, const ushort* __restrict__ Kbg,
    const ushort* __restrict__ Vtg, float* __restrict__ Og)
{
    extern __shared__ char smem[];
    const int tid  = threadIdx.x;
    const int lane = tid & 63;
    const int wv   = tid >> 6;            // 8 waves
    char* Psh = smem + 131072 + wv * 1024;  // per-wave P [16 q][32 k] bf16, 64B rows

    // bid: xcd = w>>1 (bits 0-2), then w&1, b(2), y(2)
    const int bid = blockIdx.x;
    const int r2  = bid >> 3;
    const int w   = (bid & 7) * 2 + (r2 & 1);
    const int b   = (r2 >> 1) & 3;
    const int y   = r2 >> 3;              // 0..3
    const int qbase  = w * WSZ + y * QBLK;
    const int wqbase = qbase + wv * 16;

    const float*  Qp  = Qg  + (size_t)b * S_ * D_;
    const ushort* Kbp = Kbg + (size_t)b * S_ * D_;
    const ushort* Vtp = Vtg + (size_t)b * D_ * S_;
    float*        Op  = Og  + (size_t)b * S_ * D_;

    const float scale = 0.044194173824159216f;  // 1/sqrt(512)
    const float L2E   = 1.44269504088896f;

    // ---- Q fragments: 16 rows x 512 d, scaled, bf16 (64 VGPR) ----
    bf16x8 qf[16];
    {
        const int qrow = wqbase + (lane & 15);
        const float* qsrc = Qp + (size_t)qrow * D_ + ((lane >> 4) * 8);
        #pragma unroll
        for (int c = 0; c < 16; ++c) {
            float4 a0 = *(const float4*)(qsrc + c * 32);
            float4 a1 = *(const float4*)(qsrc + c * 32 + 4);
            bf16x8 q;
            q[0] = (__bf16)(a0.x * scale); q[1] = (__bf16)(a0.y * scale);
            q[2] = (__bf16)(a0.z * scale); q[3] = (__bf16)(a0.w * scale);
            q[4] = (__bf16)(a1.x * scale); q[5] = (__bf16)(a1.y * scale);
            q[6] = (__bf16)(a1.z * scale); q[7] = (__bf16)(a1.w * scale);
            qf[c] = q;
        }
    }

    f32x4 acc[32];
    #pragma unroll
    for (int i = 0; i < 32; ++i) acc[i] = (f32x4){0.f, 0.f, 0.f, 0.f};
    float m_r[4], l_r[4];
    #pragma unroll
    for (int r = 0; r < 4; ++r) { m_r[r] = -1e30f; l_r[r] = 0.f; }

    const int kstart = (w == 0) ? 0 : (w - 1) * WSZ;
    const int ktend  = qbase + QBLK;

    // staging: wave stages 4 K-rows + 4 Vt-row-groups per tile, zero VGPR data
    auto STAGE = [&](int bufi, int kt) {
        char* kb = smem + bufi * 65536;
        char* vb = kb + 32768;
        #pragma unroll
        for (int s2 = 0; s2 < 4; ++s2) {
            const int row = wv * 4 + s2;                       // 0..31
            const int so  = (lane * 16) ^ ((row & 7) << 4);    // pre-swizzled source
            const char* gp = (const char*)Kbp + (((size_t)(kt + row)) << 10) + so;
            GLDS(gp, kb + (row << 10));
        }
        #pragma unroll
        for (int s2 = 0; s2 < 4; ++s2) {
            const int dbase = (wv * 4 + s2) * 16;              // 0..496, 16 d-rows/inst
            const int dl    = dbase + (lane >> 2);
            const int ko    = ((lane & 3) * 16) ^ ((dl & 3) << 4);
            const char* gp  = (const char*)Vtp + (((size_t)dl) << 14) + (((size_t)kt) << 1) + ko;
            GLDS(gp, vb + (dbase << 6));
        }
    };

    STAGE(0, kstart);
    __syncthreads();   // drains vmcnt

    int cur = 0;
    for (int kt = kstart; kt < ktend; kt += KBLK) {
        if (kt + KBLK < ktend) STAGE(cur ^ 1, kt + KBLK);

        if (kt <= wqbase + 15) {
            char* Ksh = smem + cur * 65536;
            char* Vsh = Ksh + 32768;

            // ---- S = Q K^T : [16 q][32 keys] ----
            f32x4 sacc[2];
            #pragma unroll
            for (int g = 0; g < 2; ++g) {
                f32x4 s = (f32x4){0.f, 0.f, 0.f, 0.f};
                const int keyrow = g * 16 + (lane & 15);
                #pragma unroll
                for (int c = 0; c < 16; ++c) {
                    const int byte = keyrow * 1024 +
                                     ((c * 64 + (lane >> 4) * 16) ^ ((keyrow & 7) << 4));
                    bf16x8 kf = *(const bf16x8*)(Ksh + byte);
                    s = __builtin_amdgcn_mfma_f32_16x16x32_bf16(qf[c], kf, s, 0, 0, 0);
                }
                sacc[g] = s;
            }

            // ---- causal mask ----
            #pragma unroll
            for (int g = 0; g < 2; ++g) {
                if (kt + g * 16 + 15 > wqbase) {
                    const int kg = kt + g * 16 + (lane & 15);
                    #pragma unroll
                    for (int r = 0; r < 4; ++r) {
                        const int qrow = wqbase + (lane >> 4) * 4 + r;
                        if (kg > qrow) sacc[g][r] = -1e30f;
                    }
                }
            }

            // ---- tile row max ----
            float tmax[4];
            #pragma unroll
            for (int r = 0; r < 4; ++r) {
                float v = fmaxf(sacc[0][r], sacc[1][r]);
                #pragma unroll
                for (int off = 8; off >= 1; off >>= 1)
                    v = fmaxf(v, __shfl_xor(v, off));
                tmax[r] = v;
            }

            // ---- deferred-max online rescale ----
            bool need = false;
            #pragma unroll
            for (int r = 0; r < 4; ++r) need |= (tmax[r] > m_r[r] + 8.f);
            if (__any(need)) {
                #pragma unroll
                for (int r = 0; r < 4; ++r) {
                    const float mnew = fmaxf(m_r[r], tmax[r]);
                    const float f = exp2f((m_r[r] - mnew) * L2E);
                    m_r[r] = mnew;
                    l_r[r] *= f;
                    #pragma unroll
                    for (int dc = 0; dc < 32; ++dc) acc[dc][r] *= f;
                }
            }

            // ---- P = exp(S - m) -> bf16 LDS; row sums ----
            float rsum[4] = {0.f, 0.f, 0.f, 0.f};
            #pragma unroll
            for (int g = 0; g < 2; ++g) {
                #pragma unroll
                for (int r = 0; r < 4; ++r) {
                    const float p = exp2f((sacc[g][r] - m_r[r]) * L2E);
                    rsum[r] += p;
                    const int prow = (lane >> 4) * 4 + r;
                    const int byte = prow * 64 +
                                     ((g * 32 + (lane & 15) * 2) ^ (((prow >> 1) & 3) << 4));
                    *(__bf16*)(Psh + byte) = (__bf16)p;
                }
            }
            #pragma unroll
            for (int r = 0; r < 4; ++r) {
                float v = rsum[r];
                #pragma unroll
                for (int off = 8; off >= 1; off >>= 1)
                    v += __shfl_xor(v, off);
                l_r[r] += v;
            }

            // ---- O += P x V ----
            {
                const int prow  = lane & 15;
                const int pbyte = prow * 64 +
                                  (((lane >> 4) * 16) ^ (((prow >> 1) & 3) << 4));
                bf16x8 pa = *(const bf16x8*)(Psh + pbyte);
                #pragma unroll
                for (int dc = 0; dc < 32; ++dc) {
                    const int d = dc * 16 + (lane & 15);
                    const int vbyte = d * 64 +
                                      (((lane >> 4) * 16) ^ ((d & 3) << 4));
                    bf16x8 vf = *(const bf16x8*)(Vsh + vbyte);
                    acc[dc] = __builtin_amdgcn_mfma_f32_16x16x32_bf16(pa, vf, acc[dc], 0, 0, 0);
                }
            }
        }
        __syncthreads();
        cur ^= 1;
    }

    // ---- epilogue ----
    float inv[4];
    #pragma unroll
    for (int r = 0; r < 4; ++r) inv[r] = 1.0f / l_r[r];
    #pragma unroll
    for (int dc = 0; dc < 32; ++dc) {
        #pragma unroll
        for (int r = 0; r < 4; ++r) {
            const int row = wqbase + (lane >> 4) * 4 + r;
            const int col = dc * 16 + (lane & 15);
            Op[(size_t)row * D_ + col] = acc[dc][r] * inv[r];
        }
    }
}

// ---------------- fallback (R2 kernel) if ws too small ----------------
#define FB_LDS (32768 + 32768 + 4 * 1024)
__global__ __launch_bounds__(256, 2) void gats_attn_fb(
    const float* __restrict__ Qg, const float* __restrict__ Kg,
    const float* __restrict__ Vg, float* __restrict__ Og)
{
    extern __shared__ char smem[];
    char* Ksh = smem;
    char* Vsh = smem + 32768;
    const int tid  = threadIdx.x;
    const int lane = tid & 63;
    const int wv   = tid >> 6;
    char* Psh = smem + 65536 + wv * 1024;
    const int bid = blockIdx.x;
    const int wh  = bid & 7;
    const int r2  = bid >> 3;
    const int w   = wh * 2 + (r2 & 1);
    const int b   = (r2 >> 1) & 3;
    const int y   = r2 >> 3;
    const int qbase  = w * WSZ + y * 64;
    const int wqbase = qbase + wv * 16;
    const size_t boff = (size_t)b * S_ * D_;
    const float* Qp = Qg + boff; const float* Kp = Kg + boff;
    const float* Vp = Vg + boff; float* Op = Og + boff;
    const float scale = 0.044194173824159216f;
    const float L2E   = 1.44269504088896f;
    bf16x8 qf[16];
    {
        const int qrow = wqbase + (lane & 15);
        const float* qsrc = Qp + (size_t)qrow * D_ + ((lane >> 4) * 8);
        #pragma unroll
        for (int c = 0; c < 16; ++c) {
            float4 a0 = *(const float4*)(qsrc + c * 32);
            float4 a1 = *(const float4*)(qsrc + c * 32 + 4);
            bf16x8 q;
            q[0] = (__bf16)(a0.x * scale); q[1] = (__bf16)(a0.y * scale);
            q[2] = (__bf16)(a0.z * scale); q[3] = (__bf16)(a0.w * scale);
            q[4] = (__bf16)(a1.x * scale); q[5] = (__bf16)(a1.y * scale);
            q[6] = (__bf16)(a1.z * scale); q[7] = (__bf16)(a1.w * scale);
            qf[c] = q;
        }
    }
    f32x4 acc[32];
    #pragma unroll
    for (int i = 0; i < 32; ++i) acc[i] = (f32x4){0.f, 0.f, 0.f, 0.f};
    float m_r[4], l_r[4];
    #pragma unroll
    for (int r = 0; r < 4; ++r) { m_r[r] = -1e30f; l_r[r] = 0.f; }
    const int kstart = (w == 0) ? 0 : (w - 1) * WSZ;
    const int ktend  = qbase + 64;
    for (int kt = kstart; kt < ktend; kt += 32) {
        __syncthreads();
        #pragma unroll
        for (int s = 0; s < 8; ++s) {
            const int row = s * 4 + wv;
            const int dof = lane * 8;
            const float4* src = (const float4*)(Kp + (size_t)(kt + row) * D_ + dof);
            float4 a0 = src[0], a1 = src[1];
            bf16x8 kv;
            kv[0] = (__bf16)a0.x; kv[1] = (__bf16)a0.y; kv[2] = (__bf16)a0.z; kv[3] = (__bf16)a0.w;
            kv[4] = (__bf16)a1.x; kv[5] = (__bf16)a1.y; kv[6] = (__bf16)a1.z; kv[7] = (__bf16)a1.w;
            const int byte = row * 1024 + ((dof * 2) ^ ((row & 7) << 4));
            *(bf16x8*)(Ksh + byte) = kv;
        }
        #pragma unroll
        for (int h = 0; h < 2; ++h) {
            const int d = tid + h * 256;
            #pragma unroll
            for (int it = 0; it < 4; ++it) {
                float vvv[8];
                #pragma unroll
                for (int j = 0; j < 8; ++j)
                    vvv[j] = Vp[(size_t)(kt + it * 8 + j) * D_ + d];
                bf16x8 vb;
                #pragma unroll
                for (int j = 0; j < 8; ++j) vb[j] = (__bf16)vvv[j];
                const int byte = d * 64 + ((it * 16) ^ (((d >> 1) & 3) << 4));
                *(bf16x8*)(Vsh + byte) = vb;
            }
        }
        __syncthreads();
        if (kt > wqbase + 15) continue;
        f32x4 sacc[2];
        #pragma unroll
        for (int g = 0; g < 2; ++g) {
            f32x4 s = (f32x4){0.f, 0.f, 0.f, 0.f};
            const int keyrow = g * 16 + (lane & 15);
            #pragma unroll
            for (int c = 0; c < 16; ++c) {
                const int byte = keyrow * 1024 +
                                 ((c * 64 + (lane >> 4) * 16) ^ ((keyrow & 7) << 4));
                bf16x8 kf = *(const bf16x8*)(Ksh + byte);
                s = __builtin_amdgcn_mfma_f32_16x16x32_bf16(qf[c], kf, s, 0, 0, 0);
            }
            sacc[g] = s;
        }
        #pragma unroll
        for (int g = 0; g < 2; ++g) {
            if (kt + g * 16 + 15 > wqbase) {
                const int kg = kt + g * 16 + (lane & 15);
                #pragma unroll
                for (int r = 0; r < 4; ++r) {
                    const int qrow = wqbase + (lane >> 4) * 4 + r;
                    if (kg > qrow) sacc[g][r] = -1e30f;
                }
            }
        }
        float tmax[4];
        #pragma unroll
        for (int r = 0; r < 4; ++r) {
            float v = fmaxf(sacc[0][r], sacc[1][r]);
            #pragma unroll
            for (int off = 8; off >= 1; off >>= 1)
                v = fmaxf(v, __shfl_xor(v, off));
            tmax[r] = v;
        }
        bool need = false;
        #pragma unroll
        for (int r = 0; r < 4; ++r) need |= (tmax[r] > m_r[r] + 8.f);
        if (__any(need)) {
            #pragma unroll
            for (int r = 0; r < 4; ++r) {
                const float mnew = fmaxf(m_r[r], tmax[r]);
                const float f = exp2f((m_r[r] - mnew) * L2E);
                m_r[r] = mnew; l_r[r] *= f;
                #pragma unroll
                for (int dc = 0; dc < 32; ++dc) acc[dc][r] *= f;
            }
        }
        float rsum[4] = {0.f, 0.f, 0.f, 0.f};
        #pragma unroll
        for (int g = 0; g < 2; ++g) {
            #pragma unroll
            for (int r = 0; r < 4; ++r) {
                const float p = exp2f((sacc[g][r] - m_r[r]) * L2E);
                rsum[r] += p;
                const int prow = (lane >> 4) * 4 + r;
                const int byte = prow * 64 +
                                 ((g * 32 + (lane & 15) * 2) ^ (((prow >> 1) & 3) << 4));
                *(__bf16*)(Psh + byte) = (__bf16)p;
            }
        }
        #pragma unroll
        for (int r = 0; r < 4; ++r) {
            float v = rsum[r];
            #pragma unroll
            for (int off = 8; off >= 1; off >>= 1)
                v += __shfl_xor(v, off);
            l_r[r] += v;
        }
        {
            const int prow  = lane & 15;
            const int pbyte = prow * 64 +
                              (((lane >> 4) * 16) ^ (((prow >> 1) & 3) << 4));
            bf16x8 pa = *(const bf16x8*)(Psh + pbyte);
            #pragma unroll
            for (int dc = 0; dc < 32; ++dc) {
                const int d = dc * 16 + (lane & 15);
                const int vbyte = d * 64 +
                                  (((lane >> 4) * 16) ^ (((d >> 1) & 3) << 4));
                bf16x8 vf = *(const bf16x8*)(Vsh + vbyte);
                acc[dc] = __builtin_amdgcn_mfma_f32_16x16x32_bf16(pa, vf, acc[dc], 0, 0, 0);
            }
        }
    }
    float inv[4];
    #pragma unroll
    for (int r = 0; r < 4; ++r) inv[r] = 1.0f / l_r[r];
    #pragma unroll
    for (int dc = 0; dc < 32; ++dc) {
        #pragma unroll
        for (int r = 0; r < 4; ++r) {
            const int row = wqbase + (lane >> 4) * 4 + r;
            const int col = dc * 16 + (lane & 15);
            Op[(size_t)row * D_ + col] = acc[dc][r] * inv[r];
        }
    }
}

extern "C" void kernel_launch(void* const* d_in, const int* in_sizes, int n_in,
                              void* d_out, int out_size, void* d_ws, size_t ws_size,
                              hipStream_t stream) {
    const float* q = (const float*)d_in[0];   // text
    const float* k = (const float*)d_in[1];   // audio
    const float* v = (const float*)d_in[2];   // video
    float* o = (float*)d_out;

    const size_t elems = (size_t)4 * S_ * D_ * 4;   // 16,777,216 per tensor
    const size_t need  = elems * 2 * 2;             // K bf16 + Vt bf16 = 64MB
    if (ws_size >= need) {
        ushort* kb  = (ushort*)d_ws;
        ushort* vt  = kb + elems;
        cvt_k<<<dim3(8192), dim3(256), 0, stream>>>(k, kb);
        tr_v <<<dim3(4096), dim3(256), 0, stream>>>(v, vt);
        hipFuncSetAttribute((const void*)gats_attn,
                            hipFuncAttributeMaxDynamicSharedMemorySize, ATT_LDS);
        gats_attn<<<dim3(256), dim3(ATT_THREADS), ATT_LDS, stream>>>(q, kb, vt, o);
    } else {
        hipFuncSetAttribute((const void*)gats_attn_fb,
                            hipFuncAttributeMaxDynamicSharedMemorySize, FB_LDS);
        gats_attn_fb<<<dim3(512), dim3(256), FB_LDS, stream>>>(q, k, v, o);
    }
}

// Round 4
// 193.587 us; speedup vs baseline: 1.9136x; 1.4032x over previous
//
#include <hip/hip_runtime.h>
#include <hip/hip_bf16.h>

#define S_ 8192
#define D_ 512
#define WSZ 512
#define QBLK 128
#define KBLK 32
#define ATT_THREADS 512
#define ATT_LDS (2 * 65536)   // 2 x (K 32KB + Vt 32KB)

using bf16x8 = __attribute__((ext_vector_type(8))) __bf16;
using f32x4  = __attribute__((ext_vector_type(4))) float;

#define GLDS(gp, lp) __builtin_amdgcn_global_load_lds( \
    (const __attribute__((address_space(1))) void*)(gp), \
    (__attribute__((address_space(3))) void*)(lp), 16, 0, 0)

// ---------------- pre-pass 1: K fp32 -> bf16 (layout unchanged) ----------------
__global__ __launch_bounds__(256) void cvt_k(const float* __restrict__ in,
                                             ushort* __restrict__ out) {
    const size_t i = ((size_t)blockIdx.x * 256 + threadIdx.x) * 8;
    float4 a0 = *(const float4*)(in + i);
    float4 a1 = *(const float4*)(in + i + 4);
    bf16x8 o;
    o[0] = (__bf16)a0.x; o[1] = (__bf16)a0.y; o[2] = (__bf16)a0.z; o[3] = (__bf16)a0.w;
    o[4] = (__bf16)a1.x; o[5] = (__bf16)a1.y; o[6] = (__bf16)a1.z; o[7] = (__bf16)a1.w;
    *(bf16x8*)(out + i) = o;
}

// -------- pre-pass 2: V fp32 [b][s][d] -> packed swizzled Vt tiles --------
// layout: per (b, t = s/32): 32KB block; element (d, k) at
//   block*32768 + d*64 + (((k>>3)*16) ^ ((d&3)<<4)) + (k&7)*2
__global__ __launch_bounds__(256) void tr_v(const float* __restrict__ V,
                                            char* __restrict__ Vt) {
    __shared__ float tile[64][68];
    const int bid = blockIdx.x;            // 4096 = 8 dblk x 128 sblk x 4 b
    const int d0 = (bid & 7) * 64;
    const int s0 = ((bid >> 3) & 127) * 64;
    const int b  = bid >> 10;
    const int t  = threadIdx.x;
    {
        const int sl = t >> 2, cg = (t & 3) * 16;
        const float* src = V + ((size_t)b * S_ + s0 + sl) * D_ + d0 + cg;
        #pragma unroll
        for (int j = 0; j < 4; ++j) {
            float4 a = *(const float4*)(src + j * 4);
            *(float4*)&tile[sl][cg + j * 4] = a;
        }
    }
    __syncthreads();
    {
        const int dl = t >> 2, sg = (t & 3) * 16;
        const int d  = d0 + dl;
        const int tt = (s0 + sg) >> 5;
        const int k0 = (s0 + sg) & 31;         // 0 or 16
        const size_t base = ((size_t)(b * 256 + tt) * 512 + d) * 64;
        bf16x8 o0, o1;
        #pragma unroll
        for (int j = 0; j < 8; ++j) {
            o0[j] = (__bf16)tile[sg + j][dl];
            o1[j] = (__bf16)tile[sg + 8 + j][dl];
        }
        const int swz = (d & 3) << 4;
        *(bf16x8*)(Vt + base + (((k0 >> 3) * 16) ^ swz))       = o0;
        *(bf16x8*)(Vt + base + ((((k0 >> 3) + 1) * 16) ^ swz)) = o1;
    }
}

// ---------------- main attention ----------------
__global__ __launch_bounds__(ATT_THREADS, 2) void gats_attn(
    const float* __restrict__ Qg, const ushort* __restrict__ Kbg,
    const char* __restrict__ Vtg, float* __restrict__ Og)
{
    extern __shared__ char smem[];
    const int tid  = threadIdx.x;
    const int lane = tid & 63;
    const int wv   = tid >> 6;            // 8 waves
    const int h    = lane >> 4;           // 0..3
    const int lq   = lane & 15;

    // bid: xcd = w>>1 (bits 0-2), then w&1, b(2), y(2)
    const int bid = blockIdx.x;
    const int r2  = bid >> 3;
    const int w   = (bid & 7) * 2 + (r2 & 1);
    const int b   = (r2 >> 1) & 3;
    const int y   = r2 >> 3;              // 0..3
    const int qbase  = w * WSZ + y * QBLK;
    const int wqbase = qbase + wv * 16;

    const float* Qp  = Qg  + (size_t)b * S_ * D_;
    const char*  Kbp = (const char*)(Kbg + (size_t)b * S_ * D_);
    const char*  Vtp = Vtg + ((size_t)b * 256) * 32768;
    float*       Op  = Og  + (size_t)b * S_ * D_;

    const float scale = 0.044194173824159216f;  // 1/sqrt(512)
    const float L2E   = 1.44269504088896f;

    // ---- Q fragments: 16 rows x 512 d, scaled, bf16 (64 VGPR) ----
    bf16x8 qf[16];
    {
        const int qrow = wqbase + lq;
        const float* qsrc = Qp + (size_t)qrow * D_ + h * 8;
        #pragma unroll
        for (int c = 0; c < 16; ++c) {
            float4 a0 = *(const float4*)(qsrc + c * 32);
            float4 a1 = *(const float4*)(qsrc + c * 32 + 4);
            bf16x8 q;
            q[0] = (__bf16)(a0.x * scale); q[1] = (__bf16)(a0.y * scale);
            q[2] = (__bf16)(a0.z * scale); q[3] = (__bf16)(a0.w * scale);
            q[4] = (__bf16)(a1.x * scale); q[5] = (__bf16)(a1.y * scale);
            q[6] = (__bf16)(a1.z * scale); q[7] = (__bf16)(a1.w * scale);
            qf[c] = q;
        }
    }

    f32x4 acc[32];
    #pragma unroll
    for (int i = 0; i < 32; ++i) acc[i] = (f32x4){0.f, 0.f, 0.f, 0.f};
    float m_run = -1e30f, l_run = 0.f;    // softmax state for q = wqbase + lq

    const int kstart = (w == 0) ? 0 : (w - 1) * WSZ;
    const int ktend  = qbase + QBLK;

    auto STAGE = [&](int bufi, int kt) {
        char* kb = smem + bufi * 65536;
        char* vb = kb + 32768;
        #pragma unroll
        for (int s2 = 0; s2 < 4; ++s2) {
            const int row = wv * 4 + s2;                     // 0..31
            const int so  = (lane * 16) ^ ((row & 7) << 4);  // pre-swizzled source
            GLDS(Kbp + (((size_t)(kt + row)) << 10) + so, kb + (row << 10));
        }
        const char* vsrc = Vtp + (((size_t)(kt >> 5)) << 15);
        #pragma unroll
        for (int s2 = 0; s2 < 4; ++s2) {
            const int off = wv * 4096 + s2 * 1024;           // linear, swizzle baked
            GLDS(vsrc + off + lane * 16, vb + off);
        }
    };

    STAGE(0, kstart);
    int cur = 0;
    for (int kt = kstart; kt < ktend; kt += KBLK) {
        const bool hasnext = (kt + KBLK) < ktend;
        if (hasnext) {
            STAGE(cur ^ 1, kt + KBLK);
            asm volatile("s_waitcnt vmcnt(8)" ::: "memory");
        } else {
            asm volatile("s_waitcnt vmcnt(0)" ::: "memory");
        }
        __builtin_amdgcn_s_barrier();

        if (kt <= wqbase + 15) {
            char* Ksh = smem + cur * 65536;
            char* Vsh = Ksh + 32768;

            // ---- ST = K Q^T : lane holds q = lq, keys g*16 + h*4 + r ----
            f32x4 st[2];
            __builtin_amdgcn_s_setprio(1);
            #pragma unroll
            for (int g = 0; g < 2; ++g) {
                f32x4 sa = (f32x4){0.f, 0.f, 0.f, 0.f};
                f32x4 sb = (f32x4){0.f, 0.f, 0.f, 0.f};
                const int keyrow = g * 16 + lq;
                #pragma unroll
                for (int c = 0; c < 16; ++c) {
                    const int byte = keyrow * 1024 +
                                     ((c * 64 + h * 16) ^ ((keyrow & 7) << 4));
                    bf16x8 kf = *(const bf16x8*)(Ksh + byte);
                    if (c & 1) sb = __builtin_amdgcn_mfma_f32_16x16x32_bf16(kf, qf[c], sb, 0, 0, 0);
                    else       sa = __builtin_amdgcn_mfma_f32_16x16x32_bf16(kf, qf[c], sa, 0, 0, 0);
                }
                st[g] = sa + sb;
            }
            __builtin_amdgcn_s_setprio(0);

            // ---- causal mask ----
            const int qg = wqbase + lq;
            if (kt + 31 > wqbase) {
                #pragma unroll
                for (int g = 0; g < 2; ++g)
                    #pragma unroll
                    for (int r = 0; r < 4; ++r) {
                        const int key = kt + g * 16 + h * 4 + r;
                        if (key > qg) st[g][r] = -1e30f;
                    }
            }

            // ---- row max (2 shfl) ----
            float own = st[0][0];
            #pragma unroll
            for (int r = 1; r < 4; ++r) own = fmaxf(own, st[0][r]);
            #pragma unroll
            for (int r = 0; r < 4; ++r) own = fmaxf(own, st[1][r]);
            float tmax = fmaxf(own, __shfl_xor(own, 16));
            tmax = fmaxf(tmax, __shfl_xor(tmax, 32));

            // ---- deferred-max rescale ----
            if (__any(tmax > m_run + 8.f)) {
                const float mnew = fmaxf(m_run, tmax);
                const float f = exp2f((m_run - mnew) * L2E);
                m_run = mnew;
                l_run *= f;
                float fr[4];
                #pragma unroll
                for (int r = 0; r < 4; ++r) fr[r] = __shfl(f, h * 4 + r);
                #pragma unroll
                for (int dc = 0; dc < 32; ++dc)
                    #pragma unroll
                    for (int r = 0; r < 4; ++r) acc[dc][r] *= fr[r];
            }

            // ---- P = exp(S - m); sum; pack to bf16 A-frag in-register ----
            float p[2][4];
            float rs = 0.f;
            #pragma unroll
            for (int g = 0; g < 2; ++g)
                #pragma unroll
                for (int r = 0; r < 4; ++r) {
                    const float v = exp2f((st[g][r] - m_run) * L2E);
                    p[g][r] = v;
                    rs += v;
                }
            rs += __shfl_xor(rs, 16);
            rs += __shfl_xor(rs, 32);
            l_run += rs;

            uint c0, c1, c2, c3;
            asm("v_cvt_pk_bf16_f32 %0, %1, %2" : "=v"(c0) : "v"(p[0][0]), "v"(p[0][1]));
            asm("v_cvt_pk_bf16_f32 %0, %1, %2" : "=v"(c1) : "v"(p[0][2]), "v"(p[0][3]));
            asm("v_cvt_pk_bf16_f32 %0, %1, %2" : "=v"(c2) : "v"(p[1][0]), "v"(p[1][1]));
            asm("v_cvt_pk_bf16_f32 %0, %1, %2" : "=v"(c3) : "v"(p[1][2]), "v"(p[1][3]));
            const uint x16_0 = __shfl_xor((int)c0, 16), x16_1 = __shfl_xor((int)c1, 16);
            const uint x16_2 = __shfl_xor((int)c2, 16), x16_3 = __shfl_xor((int)c3, 16);
            const uint x32_0 = __shfl_xor((int)c0, 32), x32_1 = __shfl_xor((int)c1, 32);
            const uint x32_2 = __shfl_xor((int)c2, 32), x32_3 = __shfl_xor((int)c3, 32);
            const uint x48_0 = __shfl_xor((int)c0, 48), x48_1 = __shfl_xor((int)c1, 48);
            const uint x48_2 = __shfl_xor((int)c2, 48), x48_3 = __shfl_xor((int)c3, 48);
            union { uint u[4]; bf16x8 v; } pu;
            pu.u[0] = (h == 0) ? c0 : (h == 1) ? x48_0 : (h == 2) ? x32_2 : x16_2;
            pu.u[1] = (h == 0) ? c1 : (h == 1) ? x48_1 : (h == 2) ? x32_3 : x16_3;
            pu.u[2] = (h == 0) ? x16_0 : (h == 1) ? x32_0 : (h == 2) ? x48_2 : c2;
            pu.u[3] = (h == 0) ? x16_1 : (h == 1) ? x32_1 : (h == 2) ? x48_3 : c3;
            const bf16x8 pa = pu.v;

            // ---- O += P x V ----
            __builtin_amdgcn_s_setprio(1);
            #pragma unroll
            for (int dc = 0; dc < 32; ++dc) {
                const int d = dc * 16 + lq;
                const int vbyte = d * 64 + ((h * 16) ^ ((d & 3) << 4));
                bf16x8 vf = *(const bf16x8*)(Vsh + vbyte);
                acc[dc] = __builtin_amdgcn_mfma_f32_16x16x32_bf16(pa, vf, acc[dc], 0, 0, 0);
            }
            __builtin_amdgcn_s_setprio(0);
        }
        __builtin_amdgcn_s_barrier();
        cur ^= 1;
    }

    // ---- epilogue: normalize and store ----
    const float invq = 1.0f / l_run;
    float inv[4];
    #pragma unroll
    for (int r = 0; r < 4; ++r) inv[r] = __shfl(invq, h * 4 + r);
    #pragma unroll
    for (int dc = 0; dc < 32; ++dc) {
        #pragma unroll
        for (int r = 0; r < 4; ++r) {
            const int row = wqbase + h * 4 + r;
            const int col = dc * 16 + lq;
            Op[(size_t)row * D_ + col] = acc[dc][r] * inv[r];
        }
    }
}

// ---------------- fallback (no-ws path, reg-staged) ----------------
#define FB_LDS (32768 + 32768 + 4 * 1024)
__global__ __launch_bounds__(256, 2) void gats_attn_fb(
    const float* __restrict__ Qg, const float* __restrict__ Kg,
    const float* __restrict__ Vg, float* __restrict__ Og)
{
    extern __shared__ char smem[];
    char* Ksh = smem;
    char* Vsh = smem + 32768;
    const int tid  = threadIdx.x;
    const int lane = tid & 63;
    const int wv   = tid >> 6;
    char* Psh = smem + 65536 + wv * 1024;
    const int bid = blockIdx.x;
    const int wh  = bid & 7;
    const int r2  = bid >> 3;
    const int w   = wh * 2 + (r2 & 1);
    const int b   = (r2 >> 1) & 3;
    const int y   = r2 >> 3;
    const int qbase  = w * WSZ + y * 64;
    const int wqbase = qbase + wv * 16;
    const size_t boff = (size_t)b * S_ * D_;
    const float* Qp = Qg + boff; const float* Kp = Kg + boff;
    const float* Vp = Vg + boff; float* Op = Og + boff;
    const float scale = 0.044194173824159216f;
    const float L2E   = 1.44269504088896f;
    bf16x8 qf[16];
    {
        const int qrow = wqbase + (lane & 15);
        const float* qsrc = Qp + (size_t)qrow * D_ + ((lane >> 4) * 8);
        #pragma unroll
        for (int c = 0; c < 16; ++c) {
            float4 a0 = *(const float4*)(qsrc + c * 32);
            float4 a1 = *(const float4*)(qsrc + c * 32 + 4);
            bf16x8 q;
            q[0] = (__bf16)(a0.x * scale); q[1] = (__bf16)(a0.y * scale);
            q[2] = (__bf16)(a0.z * scale); q[3] = (__bf16)(a0.w * scale);
            q[4] = (__bf16)(a1.x * scale); q[5] = (__bf16)(a1.y * scale);
            q[6] = (__bf16)(a1.z * scale); q[7] = (__bf16)(a1.w * scale);
            qf[c] = q;
        }
    }
    f32x4 acc[32];
    #pragma unroll
    for (int i = 0; i < 32; ++i) acc[i] = (f32x4){0.f, 0.f, 0.f, 0.f};
    float m_r[4], l_r[4];
    #pragma unroll
    for (int r = 0; r < 4; ++r) { m_r[r] = -1e30f; l_r[r] = 0.f; }
    const int kstart = (w == 0) ? 0 : (w - 1) * WSZ;
    const int ktend  = qbase + 64;
    for (int kt = kstart; kt < ktend; kt += 32) {
        __syncthreads();
        #pragma unroll
        for (int s = 0; s < 8; ++s) {
            const int row = s * 4 + wv;
            const int dof = lane * 8;
            const float4* src = (const float4*)(Kp + (size_t)(kt + row) * D_ + dof);
            float4 a0 = src[0], a1 = src[1];
            bf16x8 kv;
            kv[0] = (__bf16)a0.x; kv[1] = (__bf16)a0.y; kv[2] = (__bf16)a0.z; kv[3] = (__bf16)a0.w;
            kv[4] = (__bf16)a1.x; kv[5] = (__bf16)a1.y; kv[6] = (__bf16)a1.z; kv[7] = (__bf16)a1.w;
            const int byte = row * 1024 + ((dof * 2) ^ ((row & 7) << 4));
            *(bf16x8*)(Ksh + byte) = kv;
        }
        #pragma unroll
        for (int hh = 0; hh < 2; ++hh) {
            const int d = tid + hh * 256;
            #pragma unroll
            for (int it = 0; it < 4; ++it) {
                float vvv[8];
                #pragma unroll
                for (int j = 0; j < 8; ++j)
                    vvv[j] = Vp[(size_t)(kt + it * 8 + j) * D_ + d];
                bf16x8 vb;
                #pragma unroll
                for (int j = 0; j < 8; ++j) vb[j] = (__bf16)vvv[j];
                const int byte = d * 64 + ((it * 16) ^ (((d >> 1) & 3) << 4));
                *(bf16x8*)(Vsh + byte) = vb;
            }
        }
        __syncthreads();
        if (kt > wqbase + 15) continue;
        f32x4 sacc[2];
        #pragma unroll
        for (int g = 0; g < 2; ++g) {
            f32x4 s = (f32x4){0.f, 0.f, 0.f, 0.f};
            const int keyrow = g * 16 + (lane & 15);
            #pragma unroll
            for (int c = 0; c < 16; ++c) {
                const int byte = keyrow * 1024 +
                                 ((c * 64 + (lane >> 4) * 16) ^ ((keyrow & 7) << 4));
                bf16x8 kf = *(const bf16x8*)(Ksh + byte);
                s = __builtin_amdgcn_mfma_f32_16x16x32_bf16(qf[c], kf, s, 0, 0, 0);
            }
            sacc[g] = s;
        }
        #pragma unroll
        for (int g = 0; g < 2; ++g) {
            if (kt + g * 16 + 15 > wqbase) {
                const int kg = kt + g * 16 + (lane & 15);
                #pragma unroll
                for (int r = 0; r < 4; ++r) {
                    const int qrow = wqbase + (lane >> 4) * 4 + r;
                    if (kg > qrow) sacc[g][r] = -1e30f;
                }
            }
        }
        float tmax[4];
        #pragma unroll
        for (int r = 0; r < 4; ++r) {
            float v = fmaxf(sacc[0][r], sacc[1][r]);
            #pragma unroll
            for (int off = 8; off >= 1; off >>= 1)
                v = fmaxf(v, __shfl_xor(v, off));
            tmax[r] = v;
        }
        bool need = false;
        #pragma unroll
        for (int r = 0; r < 4; ++r) need |= (tmax[r] > m_r[r] + 8.f);
        if (__any(need)) {
            #pragma unroll
            for (int r = 0; r < 4; ++r) {
                const float mnew = fmaxf(m_r[r], tmax[r]);
                const float f = exp2f((m_r[r] - mnew) * L2E);
                m_r[r] = mnew; l_r[r] *= f;
                #pragma unroll
                for (int dc = 0; dc < 32; ++dc) acc[dc][r] *= f;
            }
        }
        float rsum[4] = {0.f, 0.f, 0.f, 0.f};
        #pragma unroll
        for (int g = 0; g < 2; ++g) {
            #pragma unroll
            for (int r = 0; r < 4; ++r) {
                const float p = exp2f((sacc[g][r] - m_r[r]) * L2E);
                rsum[r] += p;
                const int prow = (lane >> 4) * 4 + r;
                const int byte = prow * 64 +
                                 ((g * 32 + (lane & 15) * 2) ^ (((prow >> 1) & 3) << 4));
                *(__bf16*)(Psh + byte) = (__bf16)p;
            }
        }
        #pragma unroll
        for (int r = 0; r < 4; ++r) {
            float v = rsum[r];
            #pragma unroll
            for (int off = 8; off >= 1; off >>= 1)
                v += __shfl_xor(v, off);
            l_r[r] += v;
        }
        {
            const int prow  = lane & 15;
            const int pbyte = prow * 64 +
                              (((lane >> 4) * 16) ^ (((prow >> 1) & 3) << 4));
            bf16x8 pa = *(const bf16x8*)(Psh + pbyte);
            #pragma unroll
            for (int dc = 0; dc < 32; ++dc) {
                const int d = dc * 16 + (lane & 15);
                const int vbyte = d * 64 +
                                  (((lane >> 4) * 16) ^ (((d >> 1) & 3) << 4));
                bf16x8 vf = *(const bf16x8*)(Vsh + vbyte);
                acc[dc] = __builtin_amdgcn_mfma_f32_16x16x32_bf16(pa, vf, acc[dc], 0, 0, 0);
            }
        }
    }
    float inv[4];
    #pragma unroll
    for (int r = 0; r < 4; ++r) inv[r] = 1.0f / l_r[r];
    #pragma unroll
    for (int dc = 0; dc < 32; ++dc) {
        #pragma unroll
        for (int r = 0; r < 4; ++r) {
            const int row = wqbase + (lane >> 4) * 4 + r;
            const int col = dc * 16 + (lane & 15);
            Op[(size_t)row * D_ + col] = acc[dc][r] * inv[r];
        }
    }
}

extern "C" void kernel_launch(void* const* d_in, const int* in_sizes, int n_in,
                              void* d_out, int out_size, void* d_ws, size_t ws_size,
                              hipStream_t stream) {
    const float* q = (const float*)d_in[0];   // text
    const float* k = (const float*)d_in[1];   // audio
    const float* v = (const float*)d_in[2];   // video
    float* o = (float*)d_out;

    const size_t elems = (size_t)4 * S_ * D_ * 4;   // 16,777,216 per tensor
    const size_t need  = elems * 2 * 2;             // K bf16 + Vt bf16 = 64MB
    if (ws_size >= need) {
        ushort* kb = (ushort*)d_ws;
        char*   vt = (char*)d_ws + elems * 2;
        cvt_k<<<dim3(8192), dim3(256), 0, stream>>>(k, kb);
        tr_v <<<dim3(4096), dim3(256), 0, stream>>>(v, vt);
        hipFuncSetAttribute((const void*)gats_attn,
                            hipFuncAttributeMaxDynamicSharedMemorySize, ATT_LDS);
        gats_attn<<<dim3(256), dim3(ATT_THREADS), ATT_LDS, stream>>>(q, kb, vt, o);
    } else {
        hipFuncSetAttribute((const void*)gats_attn_fb,
                            hipFuncAttributeMaxDynamicSharedMemorySize, FB_LDS);
        gats_attn_fb<<<dim3(512), dim3(256), FB_LDS, stream>>>(q, k, v, o);
    }
}

// Round 5
// 158.606 us; speedup vs baseline: 2.3357x; 1.2206x over previous
//
#include <hip/hip_runtime.h>
#include <hip/hip_bf16.h>

#define S_ 8192
#define D_ 512
#define WSZ 512
#define QBLK 128
#define KBLK 32
#define ATT_THREADS 512
#define ATT_LDS (2 * 65536)   // 2 x (K 32KB + Vt 32KB)

using bf16x8 = __attribute__((ext_vector_type(8))) __bf16;
using f32x4  = __attribute__((ext_vector_type(4))) float;

#define GLDS(gp, lp) __builtin_amdgcn_global_load_lds( \
    (const __attribute__((address_space(1))) void*)(gp), \
    (__attribute__((address_space(3))) void*)(lp), 16, 0, 0)

// ---- pre-pass 1: K fp32 [b][s][d] -> packed bf16 K-tiles ----
// Per (b, t=s/32): 32KB block of 16B units u = c*128 + row*4 + h
// holding K[b][t*32+row][c*32 + h*8 .. +7]   (c:0..15, row:0..31, h:0..3)
__global__ __launch_bounds__(256) void cvt_k(const float* __restrict__ in,
                                             ushort* __restrict__ out) {
    const int bid = blockIdx.x;               // 8192 = 8j x 256t x 4b
    const int j = bid & 7, t = (bid >> 3) & 255, b = bid >> 11;
    const int u = j * 256 + threadIdx.x;      // 0..2047
    const int c = u >> 7, row = (u >> 2) & 31, h = u & 3;
    const float* src = in + ((size_t)(b * S_ + t * 32 + row)) * D_ + c * 32 + h * 8;
    float4 a0 = *(const float4*)(src);
    float4 a1 = *(const float4*)(src + 4);
    bf16x8 o;
    o[0] = (__bf16)a0.x; o[1] = (__bf16)a0.y; o[2] = (__bf16)a0.z; o[3] = (__bf16)a0.w;
    o[4] = (__bf16)a1.x; o[5] = (__bf16)a1.y; o[6] = (__bf16)a1.z; o[7] = (__bf16)a1.w;
    *(bf16x8*)(out + (size_t)(b * 256 + t) * 16384 + u * 8) = o;
}

// ---- pre-pass 2: V fp32 [b][s][d] -> packed bf16 Vt-tiles ----
// Per (b, t=s/32): 32KB block of 16B units at dc*1024 + lq*64 + h*16
// holding V[b][t*32 + h*8 .. +7][dc*16+lq]   (dc:0..31, lq:0..15, h:0..3)
__global__ __launch_bounds__(256) void tr_v(const float* __restrict__ V,
                                            char* __restrict__ Vt) {
    __shared__ float tile[64][68];
    const int bid = blockIdx.x;               // 4096 = 8 dblk x 128 sblk x 4 b
    const int d0 = (bid & 7) * 64;
    const int s0 = ((bid >> 3) & 127) * 64;
    const int b  = bid >> 10;
    const int t  = threadIdx.x;
    {
        const int sl = t >> 2, cg = (t & 3) * 16;
        const float* src = V + ((size_t)b * S_ + s0 + sl) * D_ + d0 + cg;
        #pragma unroll
        for (int j = 0; j < 4; ++j) {
            float4 a = *(const float4*)(src + j * 4);
            *(float4*)&tile[sl][cg + j * 4] = a;
        }
    }
    __syncthreads();
    {
        const int dl = t >> 2, sg = (t & 3) * 16;
        const int d  = d0 + dl;
        const int tt = (s0 + sg) >> 5;
        const int h  = ((s0 + sg) & 31) >> 3;      // 0 or 2
        bf16x8 o0, o1;
        #pragma unroll
        for (int j = 0; j < 8; ++j) {
            o0[j] = (__bf16)tile[sg + j][dl];
            o1[j] = (__bf16)tile[sg + 8 + j][dl];
        }
        const size_t base = (size_t)(b * 256 + tt) * 32768 +
                            (d >> 4) * 1024 + (d & 15) * 64;
        *(bf16x8*)(Vt + base + h * 16)       = o0;
        *(bf16x8*)(Vt + base + (h + 1) * 16) = o1;
    }
}

// ---------------- main attention ----------------
__global__ __launch_bounds__(ATT_THREADS, 2) void gats_attn(
    const float* __restrict__ Qg, const char* __restrict__ Kbg,
    const char* __restrict__ Vtg, float* __restrict__ Og)
{
    extern __shared__ char smem[];
    const int tid  = threadIdx.x;
    const int lane = tid & 63;
    const int wv   = tid >> 6;            // 8 waves
    const int h    = lane >> 4;           // 0..3
    const int lq   = lane & 15;
    const int laneK = lq * 64 + h * 16;   // shared per-lane LDS read offset

    // bid: xcd = w>>1 (bits 0-2), then w&1, b(2), y(2)
    const int bid = blockIdx.x;
    const int r2  = bid >> 3;
    const int w   = (bid & 7) * 2 + (r2 & 1);
    const int b   = (r2 >> 1) & 3;
    const int y   = r2 >> 3;              // 0..3
    const int qbase  = w * WSZ + y * QBLK;
    const int wqbase = qbase + wv * 16;

    const float* Qp  = Qg  + (size_t)b * S_ * D_;
    const char*  Kbp = Kbg + (size_t)b * 256 * 32768;
    const char*  Vtp = Vtg + (size_t)b * 256 * 32768;
    float*       Op  = Og  + (size_t)b * S_ * D_;

    const float scale = 0.044194173824159216f;  // 1/sqrt(512)
    const float L2E   = 1.44269504088896f;

    // ---- Q fragments: 16 rows x 512 d, scaled, bf16 (64 VGPR) ----
    bf16x8 qf[16];
    {
        const int qrow = wqbase + lq;
        const float* qsrc = Qp + (size_t)qrow * D_ + h * 8;
        #pragma unroll
        for (int c = 0; c < 16; ++c) {
            float4 a0 = *(const float4*)(qsrc + c * 32);
            float4 a1 = *(const float4*)(qsrc + c * 32 + 4);
            bf16x8 q;
            q[0] = (__bf16)(a0.x * scale); q[1] = (__bf16)(a0.y * scale);
            q[2] = (__bf16)(a0.z * scale); q[3] = (__bf16)(a0.w * scale);
            q[4] = (__bf16)(a1.x * scale); q[5] = (__bf16)(a1.y * scale);
            q[6] = (__bf16)(a1.z * scale); q[7] = (__bf16)(a1.w * scale);
            qf[c] = q;
        }
    }

    f32x4 acc[32];
    #pragma unroll
    for (int i = 0; i < 32; ++i) acc[i] = (f32x4){0.f, 0.f, 0.f, 0.f};
    float m_run = -1e30f, l_run = 0.f;

    const int kstart = (w == 0) ? 0 : (w - 1) * WSZ;
    const int ktend  = qbase + QBLK;

    // staging: pure linear copy of the packed 32KB K-block + 32KB V-block
    auto STAGE = [&](int bufi, int kt) {
        char* kb = smem + bufi * 65536;
        char* vb = kb + 32768;
        const size_t tb = ((size_t)(kt >> 5)) << 15;
        const char* ksrc = Kbp + tb;
        const char* vsrc = Vtp + tb;
        #pragma unroll
        for (int s2 = 0; s2 < 4; ++s2) {
            const int off = wv * 4096 + s2 * 1024;
            GLDS(ksrc + off + lane * 16, kb + off);
            GLDS(vsrc + off + lane * 16, vb + off);
        }
    };

    STAGE(0, kstart);
    int cur = 0;
    for (int kt = kstart; kt < ktend; kt += KBLK) {
        const bool hasnext = (kt + KBLK) < ktend;
        if (hasnext) {
            STAGE(cur ^ 1, kt + KBLK);
            asm volatile("s_waitcnt vmcnt(8)" ::: "memory");
        } else {
            asm volatile("s_waitcnt vmcnt(0)" ::: "memory");
        }
        __builtin_amdgcn_s_barrier();

        if (kt <= wqbase + 15) {
            char* Ksh = smem + cur * 65536;
            char* Vsh = Ksh + 32768;

            // ---- ST = K Q^T : lane holds q = lq, keys g*16 + h*4 + r ----
            f32x4 st[2];
            __builtin_amdgcn_s_setprio(1);
            #pragma unroll
            for (int g = 0; g < 2; ++g) {
                f32x4 sa = (f32x4){0.f, 0.f, 0.f, 0.f};
                f32x4 sb = (f32x4){0.f, 0.f, 0.f, 0.f};
                #pragma unroll
                for (int c = 0; c < 16; ++c) {
                    // conflict-free: contiguous 1KB per instruction
                    const int byte = c * 2048 + g * 1024 + laneK;
                    bf16x8 kf = *(const bf16x8*)(Ksh + byte);
                    if (c & 1) sb = __builtin_amdgcn_mfma_f32_16x16x32_bf16(kf, qf[c], sb, 0, 0, 0);
                    else       sa = __builtin_amdgcn_mfma_f32_16x16x32_bf16(kf, qf[c], sa, 0, 0, 0);
                }
                st[g] = sa + sb;
            }
            __builtin_amdgcn_s_setprio(0);

            // ---- causal mask ----
            const int qg = wqbase + lq;
            if (kt + 31 > wqbase) {
                #pragma unroll
                for (int g = 0; g < 2; ++g)
                    #pragma unroll
                    for (int r = 0; r < 4; ++r) {
                        const int key = kt + g * 16 + h * 4 + r;
                        if (key > qg) st[g][r] = -1e30f;
                    }
            }

            // ---- row max (2 shfl) ----
            float own = st[0][0];
            #pragma unroll
            for (int r = 1; r < 4; ++r) own = fmaxf(own, st[0][r]);
            #pragma unroll
            for (int r = 0; r < 4; ++r) own = fmaxf(own, st[1][r]);
            float tmax = fmaxf(own, __shfl_xor(own, 16));
            tmax = fmaxf(tmax, __shfl_xor(tmax, 32));

            // ---- deferred-max rescale ----
            if (__any(tmax > m_run + 8.f)) {
                const float mnew = fmaxf(m_run, tmax);
                const float f = exp2f((m_run - mnew) * L2E);
                m_run = mnew;
                l_run *= f;
                float fr[4];
                #pragma unroll
                for (int r = 0; r < 4; ++r) fr[r] = __shfl(f, h * 4 + r);
                #pragma unroll
                for (int dc = 0; dc < 32; ++dc)
                    #pragma unroll
                    for (int r = 0; r < 4; ++r) acc[dc][r] *= fr[r];
            }

            // ---- P = exp(S - m); sum; pack to bf16 A-frag in-register ----
            float p[2][4];
            float rs = 0.f;
            #pragma unroll
            for (int g = 0; g < 2; ++g)
                #pragma unroll
                for (int r = 0; r < 4; ++r) {
                    const float v = exp2f((st[g][r] - m_run) * L2E);
                    p[g][r] = v;
                    rs += v;
                }
            rs += __shfl_xor(rs, 16);
            rs += __shfl_xor(rs, 32);
            l_run += rs;

            uint c0, c1, c2, c3;
            asm("v_cvt_pk_bf16_f32 %0, %1, %2" : "=v"(c0) : "v"(p[0][0]), "v"(p[0][1]));
            asm("v_cvt_pk_bf16_f32 %0, %1, %2" : "=v"(c1) : "v"(p[0][2]), "v"(p[0][3]));
            asm("v_cvt_pk_bf16_f32 %0, %1, %2" : "=v"(c2) : "v"(p[1][0]), "v"(p[1][1]));
            asm("v_cvt_pk_bf16_f32 %0, %1, %2" : "=v"(c3) : "v"(p[1][2]), "v"(p[1][3]));
            const uint x16_0 = __shfl_xor((int)c0, 16), x16_1 = __shfl_xor((int)c1, 16);
            const uint x16_2 = __shfl_xor((int)c2, 16), x16_3 = __shfl_xor((int)c3, 16);
            const uint x32_0 = __shfl_xor((int)c0, 32), x32_1 = __shfl_xor((int)c1, 32);
            const uint x32_2 = __shfl_xor((int)c2, 32), x32_3 = __shfl_xor((int)c3, 32);
            const uint x48_0 = __shfl_xor((int)c0, 48), x48_1 = __shfl_xor((int)c1, 48);
            const uint x48_2 = __shfl_xor((int)c2, 48), x48_3 = __shfl_xor((int)c3, 48);
            union { uint u[4]; bf16x8 v; } pu;
            pu.u[0] = (h == 0) ? c0 : (h == 1) ? x48_0 : (h == 2) ? x32_2 : x16_2;
            pu.u[1] = (h == 0) ? c1 : (h == 1) ? x48_1 : (h == 2) ? x32_3 : x16_3;
            pu.u[2] = (h == 0) ? x16_0 : (h == 1) ? x32_0 : (h == 2) ? x48_2 : c2;
            pu.u[3] = (h == 0) ? x16_1 : (h == 1) ? x32_1 : (h == 2) ? x48_3 : c3;
            const bf16x8 pa = pu.v;

            // ---- O += P x V ----
            __builtin_amdgcn_s_setprio(1);
            #pragma unroll
            for (int dc = 0; dc < 32; ++dc) {
                // conflict-free: contiguous 1KB per instruction
                bf16x8 vf = *(const bf16x8*)(Vsh + dc * 1024 + laneK);
                acc[dc] = __builtin_amdgcn_mfma_f32_16x16x32_bf16(pa, vf, acc[dc], 0, 0, 0);
            }
            __builtin_amdgcn_s_setprio(0);
        }
        __builtin_amdgcn_s_barrier();
        cur ^= 1;
    }

    // ---- epilogue: normalize and store ----
    const float invq = 1.0f / l_run;
    float inv[4];
    #pragma unroll
    for (int r = 0; r < 4; ++r) inv[r] = __shfl(invq, h * 4 + r);
    #pragma unroll
    for (int dc = 0; dc < 32; ++dc) {
        #pragma unroll
        for (int r = 0; r < 4; ++r) {
            const int row = wqbase + h * 4 + r;
            const int col = dc * 16 + lq;
            Op[(size_t)row * D_ + col] = acc[dc][r] * inv[r];
        }
    }
}

// ---------------- fallback (no-ws path, reg-staged) ----------------
#define FB_LDS (32768 + 32768 + 4 * 1024)
__global__ __launch_bounds__(256, 2) void gats_attn_fb(
    const float* __restrict__ Qg, const float* __restrict__ Kg,
    const float* __restrict__ Vg, float* __restrict__ Og)
{
    extern __shared__ char smem[];
    char* Ksh = smem;
    char* Vsh = smem + 32768;
    const int tid  = threadIdx.x;
    const int lane = tid & 63;
    const int wv   = tid >> 6;
    char* Psh = smem + 65536 + wv * 1024;
    const int bid = blockIdx.x;
    const int wh  = bid & 7;
    const int r2  = bid >> 3;
    const int w   = wh * 2 + (r2 & 1);
    const int b   = (r2 >> 1) & 3;
    const int y   = r2 >> 3;
    const int qbase  = w * WSZ + y * 64;
    const int wqbase = qbase + wv * 16;
    const size_t boff = (size_t)b * S_ * D_;
    const float* Qp = Qg + boff; const float* Kp = Kg + boff;
    const float* Vp = Vg + boff; float* Op = Og + boff;
    const float scale = 0.044194173824159216f;
    const float L2E   = 1.44269504088896f;
    bf16x8 qf[16];
    {
        const int qrow = wqbase + (lane & 15);
        const float* qsrc = Qp + (size_t)qrow * D_ + ((lane >> 4) * 8);
        #pragma unroll
        for (int c = 0; c < 16; ++c) {
            float4 a0 = *(const float4*)(qsrc + c * 32);
            float4 a1 = *(const float4*)(qsrc + c * 32 + 4);
            bf16x8 q;
            q[0] = (__bf16)(a0.x * scale); q[1] = (__bf16)(a0.y * scale);
            q[2] = (__bf16)(a0.z * scale); q[3] = (__bf16)(a0.w * scale);
            q[4] = (__bf16)(a1.x * scale); q[5] = (__bf16)(a1.y * scale);
            q[6] = (__bf16)(a1.z * scale); q[7] = (__bf16)(a1.w * scale);
            qf[c] = q;
        }
    }
    f32x4 acc[32];
    #pragma unroll
    for (int i = 0; i < 32; ++i) acc[i] = (f32x4){0.f, 0.f, 0.f, 0.f};
    float m_r[4], l_r[4];
    #pragma unroll
    for (int r = 0; r < 4; ++r) { m_r[r] = -1e30f; l_r[r] = 0.f; }
    const int kstart = (w == 0) ? 0 : (w - 1) * WSZ;
    const int ktend  = qbase + 64;
    for (int kt = kstart; kt < ktend; kt += 32) {
        __syncthreads();
        #pragma unroll
        for (int s = 0; s < 8; ++s) {
            const int row = s * 4 + wv;
            const int dof = lane * 8;
            const float4* src = (const float4*)(Kp + (size_t)(kt + row) * D_ + dof);
            float4 a0 = src[0], a1 = src[1];
            bf16x8 kv;
            kv[0] = (__bf16)a0.x; kv[1] = (__bf16)a0.y; kv[2] = (__bf16)a0.z; kv[3] = (__bf16)a0.w;
            kv[4] = (__bf16)a1.x; kv[5] = (__bf16)a1.y; kv[6] = (__bf16)a1.z; kv[7] = (__bf16)a1.w;
            const int byte = row * 1024 + ((dof * 2) ^ ((row & 7) << 4));
            *(bf16x8*)(Ksh + byte) = kv;
        }
        #pragma unroll
        for (int hh = 0; hh < 2; ++hh) {
            const int d = tid + hh * 256;
            #pragma unroll
            for (int it = 0; it < 4; ++it) {
                float vvv[8];
                #pragma unroll
                for (int j = 0; j < 8; ++j)
                    vvv[j] = Vp[(size_t)(kt + it * 8 + j) * D_ + d];
                bf16x8 vb;
                #pragma unroll
                for (int j = 0; j < 8; ++j) vb[j] = (__bf16)vvv[j];
                const int byte = d * 64 + ((it * 16) ^ (((d >> 1) & 3) << 4));
                *(bf16x8*)(Vsh + byte) = vb;
            }
        }
        __syncthreads();
        if (kt > wqbase + 15) continue;
        f32x4 sacc[2];
        #pragma unroll
        for (int g = 0; g < 2; ++g) {
            f32x4 s = (f32x4){0.f, 0.f, 0.f, 0.f};
            const int keyrow = g * 16 + (lane & 15);
            #pragma unroll
            for (int c = 0; c < 16; ++c) {
                const int byte = keyrow * 1024 +
                                 ((c * 64 + (lane >> 4) * 16) ^ ((keyrow & 7) << 4));
                bf16x8 kf = *(const bf16x8*)(Ksh + byte);
                s = __builtin_amdgcn_mfma_f32_16x16x32_bf16(qf[c], kf, s, 0, 0, 0);
            }
            sacc[g] = s;
        }
        #pragma unroll
        for (int g = 0; g < 2; ++g) {
            if (kt + g * 16 + 15 > wqbase) {
                const int kg = kt + g * 16 + (lane & 15);
                #pragma unroll
                for (int r = 0; r < 4; ++r) {
                    const int qrow = wqbase + (lane >> 4) * 4 + r;
                    if (kg > qrow) sacc[g][r] = -1e30f;
                }
            }
        }
        float tmax[4];
        #pragma unroll
        for (int r = 0; r < 4; ++r) {
            float v = fmaxf(sacc[0][r], sacc[1][r]);
            #pragma unroll
            for (int off = 8; off >= 1; off >>= 1)
                v = fmaxf(v, __shfl_xor(v, off));
            tmax[r] = v;
        }
        bool need = false;
        #pragma unroll
        for (int r = 0; r < 4; ++r) need |= (tmax[r] > m_r[r] + 8.f);
        if (__any(need)) {
            #pragma unroll
            for (int r = 0; r < 4; ++r) {
                const float mnew = fmaxf(m_r[r], tmax[r]);
                const float f = exp2f((m_r[r] - mnew) * L2E);
                m_r[r] = mnew; l_r[r] *= f;
                #pragma unroll
                for (int dc = 0; dc < 32; ++dc) acc[dc][r] *= f;
            }
        }
        float rsum[4] = {0.f, 0.f, 0.f, 0.f};
        #pragma unroll
        for (int g = 0; g < 2; ++g) {
            #pragma unroll
            for (int r = 0; r < 4; ++r) {
                const float p = exp2f((sacc[g][r] - m_r[r]) * L2E);
                rsum[r] += p;
                const int prow = (lane >> 4) * 4 + r;
                const int byte = prow * 64 +
                                 ((g * 32 + (lane & 15) * 2) ^ (((prow >> 1) & 3) << 4));
                *(__bf16*)(Psh + byte) = (__bf16)p;
            }
        }
        #pragma unroll
        for (int r = 0; r < 4; ++r) {
            float v = rsum[r];
            #pragma unroll
            for (int off = 8; off >= 1; off >>= 1)
                v += __shfl_xor(v, off);
            l_r[r] += v;
        }
        {
            const int prow  = lane & 15;
            const int pbyte = prow * 64 +
                              (((lane >> 4) * 16) ^ (((prow >> 1) & 3) << 4));
            bf16x8 pa = *(const bf16x8*)(Psh + pbyte);
            #pragma unroll
            for (int dc = 0; dc < 32; ++dc) {
                const int d = dc * 16 + (lane & 15);
                const int vbyte = d * 64 +
                                  (((lane >> 4) * 16) ^ (((d >> 1) & 3) << 4));
                bf16x8 vf = *(const bf16x8*)(Vsh + vbyte);
                acc[dc] = __builtin_amdgcn_mfma_f32_16x16x32_bf16(pa, vf, acc[dc], 0, 0, 0);
            }
        }
    }
    float inv[4];
    #pragma unroll
    for (int r = 0; r < 4; ++r) inv[r] = 1.0f / l_r[r];
    #pragma unroll
    for (int dc = 0; dc < 32; ++dc) {
        #pragma unroll
        for (int r = 0; r < 4; ++r) {
            const int row = wqbase + (lane >> 4) * 4 + r;
            const int col = dc * 16 + (lane & 15);
            Op[(size_t)row * D_ + col] = acc[dc][r] * inv[r];
        }
    }
}

extern "C" void kernel_launch(void* const* d_in, const int* in_sizes, int n_in,
                              void* d_out, int out_size, void* d_ws, size_t ws_size,
                              hipStream_t stream) {
    const float* q = (const float*)d_in[0];   // text
    const float* k = (const float*)d_in[1];   // audio
    const float* v = (const float*)d_in[2];   // video
    float* o = (float*)d_out;

    const size_t elems = (size_t)4 * S_ * D_ * 4;   // 16,777,216 per tensor
    const size_t need  = elems * 2 * 2;             // K bf16 + Vt bf16 = 64MB
    if (ws_size >= need) {
        char* kb = (char*)d_ws;
        char* vt = (char*)d_ws + elems * 2;
        cvt_k<<<dim3(8192), dim3(256), 0, stream>>>(k, (ushort*)kb);
        tr_v <<<dim3(4096), dim3(256), 0, stream>>>(v, vt);
        hipFuncSetAttribute((const void*)gats_attn,
                            hipFuncAttributeMaxDynamicSharedMemorySize, ATT_LDS);
        gats_attn<<<dim3(256), dim3(ATT_THREADS), ATT_LDS, stream>>>(q, kb, vt, o);
    } else {
        hipFuncSetAttribute((const void*)gats_attn_fb,
                            hipFuncAttributeMaxDynamicSharedMemorySize, FB_LDS);
        gats_attn_fb<<<dim3(512), dim3(256), FB_LDS, stream>>>(q, k, v, o);
    }
}

// Round 6
// 147.240 us; speedup vs baseline: 2.5160x; 1.0772x over previous
//
#include <hip/hip_runtime.h>
#include <hip/hip_bf16.h>

#define S_ 8192
#define D_ 512
#define WSZ 512
#define QBLK 128
#define KBLK 32
#define ATT_THREADS 512
#define PREG 131072
#define PSTRIDE 2560
#define ATT_LDS (PREG + 4 * PSTRIDE)   // 2x(K32K+V32K) dbuf + 4 pair P/f regions

using bf16x8 = __attribute__((ext_vector_type(8))) __bf16;
using f32x4  = __attribute__((ext_vector_type(4))) float;
using f32x16 = __attribute__((ext_vector_type(16))) float;

#define GLDS(gp, lp) __builtin_amdgcn_global_load_lds( \
    (const __attribute__((address_space(1))) void*)(gp), \
    (__attribute__((address_space(3))) void*)(lp), 16, 0, 0)

// ---- pre-pass 1: K fp32 [b][s][d] -> packed bf16 K-tiles (unchanged) ----
// Per (b, t=s/32): 32KB block of 16B units u = c*128 + row*4 + h
// holding K[b][t*32+row][c*32 + h*8 .. +7]
__global__ __launch_bounds__(256) void cvt_k(const float* __restrict__ in,
                                             ushort* __restrict__ out) {
    const int bid = blockIdx.x;               // 8192 = 8j x 256t x 4b
    const int j = bid & 7, t = (bid >> 3) & 255, b = bid >> 11;
    const int u = j * 256 + threadIdx.x;      // 0..2047
    const int c = u >> 7, row = (u >> 2) & 31, h = u & 3;
    const float* src = in + ((size_t)(b * S_ + t * 32 + row)) * D_ + c * 32 + h * 8;
    float4 a0 = *(const float4*)(src);
    float4 a1 = *(const float4*)(src + 4);
    bf16x8 o;
    o[0] = (__bf16)a0.x; o[1] = (__bf16)a0.y; o[2] = (__bf16)a0.z; o[3] = (__bf16)a0.w;
    o[4] = (__bf16)a1.x; o[5] = (__bf16)a1.y; o[6] = (__bf16)a1.z; o[7] = (__bf16)a1.w;
    *(bf16x8*)(out + (size_t)(b * 256 + t) * 16384 + u * 8) = o;
}

// ---- pre-pass 2: V fp32 [b][s][d] -> packed bf16 Vt-tiles for 32x32x16 PV ----
// Per (b, t=s/32): 32KB; element V[t*32+k][d] lives in 16B unit (8 consecutive k at fixed d):
//   addr = (d>>5)*2048 + (k>>4)*1024 + ((k>>3)&1)*512 + (d&31)*16
__global__ __launch_bounds__(256) void tr_v(const float* __restrict__ V,
                                            char* __restrict__ Vt) {
    __shared__ float tile[64][68];
    const int bid = blockIdx.x;               // 4096 = 8 dblk x 128 sblk x 4 b
    const int d0 = (bid & 7) * 64;
    const int s0 = ((bid >> 3) & 127) * 64;
    const int b  = bid >> 10;
    const int t  = threadIdx.x;
    {
        const int sl = t >> 2, cg = (t & 3) * 16;
        const float* src = V + ((size_t)b * S_ + s0 + sl) * D_ + d0 + cg;
        #pragma unroll
        for (int j = 0; j < 4; ++j)
            *(float4*)&tile[sl][cg + j * 4] = *(const float4*)(src + j * 4);
    }
    __syncthreads();
    {
        const int dl = t >> 2, sg = (t & 3) * 16;
        const int d  = d0 + dl;
        const int tt = (s0 + sg) >> 5;
        const int kk = (s0 + sg) & 31;         // 0 or 16
        bf16x8 o0, o1;
        #pragma unroll
        for (int j = 0; j < 8; ++j) {
            o0[j] = (__bf16)tile[sg + j][dl];
            o1[j] = (__bf16)tile[sg + 8 + j][dl];
        }
        char* base = Vt + (size_t)(b * 256 + tt) * 32768 +
                     (d >> 5) * 2048 + (d & 31) * 16;
        *(bf16x8*)(base + (kk >> 4) * 1024)       = o0;   // keys kk..kk+7
        *(bf16x8*)(base + (kk >> 4) * 1024 + 512) = o1;   // keys kk+8..kk+15
    }
}

// ---------------- main attention ----------------
__global__ __launch_bounds__(ATT_THREADS, 2) void gats_attn(
    const float* __restrict__ Qg, const char* __restrict__ Kbg,
    const char* __restrict__ Vtg, float* __restrict__ Og)
{
    extern __shared__ char smem[];
    const int tid  = threadIdx.x;
    const int lane = tid & 63;
    const int wv   = tid >> 6;            // 8 waves
    const int h    = lane >> 4;           // 0..3 (QK quadrant)
    const int lq   = lane & 15;
    const int hh   = lane >> 5;           // 0..1 (32-wide half)
    const int l31  = lane & 31;
    const int u    = wv & 1;              // d-half owner within pair
    const int pr   = wv >> 1;             // pair id 0..3
    char* Pp = smem + PREG + pr * PSTRIDE;  // P [32q x 32k] bf16, octet layout
    char* Pf = Pp + 2048;                   // f/l table 128B + flags 8B
    const int laneK = lq * 64 + h * 16;

    // bid: xcd = w>>1 (bits 0-2), then w&1, b(2), y(2)
    const int bid = blockIdx.x;
    const int r2  = bid >> 3;
    const int w   = (bid & 7) * 2 + (r2 & 1);
    const int b   = (r2 >> 1) & 3;
    const int y   = r2 >> 3;              // 0..3
    const int qbase    = w * WSZ + y * QBLK;
    const int pairbase = qbase + pr * 32;
    const int wqbase   = qbase + wv * 16;

    const float* Qp  = Qg  + (size_t)b * S_ * D_;
    const char*  Kbp = Kbg + (size_t)b * 256 * 32768;
    const char*  Vtp = Vtg + (size_t)b * 256 * 32768;
    float*       Op  = Og  + (size_t)b * S_ * D_;

    const float scale = 0.044194173824159216f;  // 1/sqrt(512)
    const float L2E   = 1.44269504088896f;

    // ---- Q fragments: own 16 rows x 512 d, scaled, bf16 (64 VGPR) ----
    bf16x8 qf[16];
    {
        const int qrow = wqbase + lq;
        const float* qsrc = Qp + (size_t)qrow * D_ + h * 8;
        #pragma unroll
        for (int c = 0; c < 16; ++c) {
            float4 a0 = *(const float4*)(qsrc + c * 32);
            float4 a1 = *(const float4*)(qsrc + c * 32 + 4);
            bf16x8 q;
            q[0] = (__bf16)(a0.x * scale); q[1] = (__bf16)(a0.y * scale);
            q[2] = (__bf16)(a0.z * scale); q[3] = (__bf16)(a0.w * scale);
            q[4] = (__bf16)(a1.x * scale); q[5] = (__bf16)(a1.y * scale);
            q[6] = (__bf16)(a1.z * scale); q[7] = (__bf16)(a1.w * scale);
            qf[c] = q;
        }
    }

    // acc: pair's 32 q x my 256-d half, as 8 x 32x32 C-tiles
    f32x16 acc[8];
    #pragma unroll
    for (int dt = 0; dt < 8; ++dt)
        #pragma unroll
        for (int rg = 0; rg < 16; ++rg) acc[dt][rg] = 0.f;
    float m_run = -1e30f, l_run = 0.f;    // state for q = wqbase + lq (owner)

    const int kstart = (w == 0) ? 0 : (w - 1) * WSZ;
    const int ktend  = qbase + QBLK;

    auto STAGE = [&](int bufi, int kt) {
        char* kb = smem + bufi * 65536;
        char* vb = kb + 32768;
        const size_t tb = ((size_t)(kt >> 5)) << 15;
        const char* ksrc = Kbp + tb;
        const char* vsrc = Vtp + tb;
        #pragma unroll
        for (int s2 = 0; s2 < 4; ++s2) {
            const int off = wv * 4096 + s2 * 1024;
            GLDS(ksrc + off + lane * 16, kb + off);
            GLDS(vsrc + off + lane * 16, vb + off);
        }
    };

    STAGE(0, kstart);
    int cur = 0;
    for (int kt = kstart; kt < ktend; kt += KBLK) {
        const bool hasnext = (kt + KBLK) < ktend;
        if (hasnext) {
            STAGE(cur ^ 1, kt + KBLK);
            asm volatile("s_waitcnt vmcnt(8)" ::: "memory");
        } else {
            asm volatile("s_waitcnt vmcnt(0)" ::: "memory");
        }
        __builtin_amdgcn_s_barrier();   // [#1] cur buffers ready

        const bool active = (kt <= pairbase + 31);
        char* Ksh = smem + cur * 65536;
        char* Vsh = Ksh + 32768;

        if (active) {
            // ---- ST = K Q^T (16x16x32, verified): lane q=lq, keys g*16+h*4+r ----
            f32x4 st[2];
            __builtin_amdgcn_s_setprio(1);
            #pragma unroll
            for (int g = 0; g < 2; ++g) {
                f32x4 sa = (f32x4){0.f, 0.f, 0.f, 0.f};
                f32x4 sb = (f32x4){0.f, 0.f, 0.f, 0.f};
                #pragma unroll
                for (int c = 0; c < 16; ++c) {
                    const int byte = c * 2048 + g * 1024 + laneK;
                    bf16x8 kf = *(const bf16x8*)(Ksh + byte);
                    if (c & 1) sb = __builtin_amdgcn_mfma_f32_16x16x32_bf16(kf, qf[c], sb, 0, 0, 0);
                    else       sa = __builtin_amdgcn_mfma_f32_16x16x32_bf16(kf, qf[c], sa, 0, 0, 0);
                }
                st[g] = sa + sb;
            }
            __builtin_amdgcn_s_setprio(0);

            // ---- causal mask ----
            const int qg = wqbase + lq;
            if (kt + 31 > wqbase) {
                #pragma unroll
                for (int g = 0; g < 2; ++g)
                    #pragma unroll
                    for (int r = 0; r < 4; ++r) {
                        const int key = kt + g * 16 + h * 4 + r;
                        if (key > qg) st[g][r] = -1e30f;
                    }
            }

            // ---- row max (2 shfl) ----
            float own = fmaxf(fmaxf(fmaxf(st[0][0], st[0][1]), fmaxf(st[0][2], st[0][3])),
                              fmaxf(fmaxf(st[1][0], st[1][1]), fmaxf(st[1][2], st[1][3])));
            float tmax = fmaxf(own, __shfl_xor(own, 16));
            tmax = fmaxf(tmax, __shfl_xor(tmax, 32));

            // ---- deferred-max; f goes to LDS table for the pair ----
            const bool anyneed = __any(tmax > m_run + 8.f);
            float f_val = 1.0f;
            if (anyneed) {
                const float mnew = fmaxf(m_run, tmax);
                f_val = exp2f((m_run - mnew) * L2E);
                m_run = mnew;
                l_run *= f_val;
            }

            // ---- P = exp(S - m); row sum; pack bf16; write P half to pair LDS ----
            const float p00 = exp2f((st[0][0] - m_run) * L2E);
            const float p01 = exp2f((st[0][1] - m_run) * L2E);
            const float p02 = exp2f((st[0][2] - m_run) * L2E);
            const float p03 = exp2f((st[0][3] - m_run) * L2E);
            const float p10 = exp2f((st[1][0] - m_run) * L2E);
            const float p11 = exp2f((st[1][1] - m_run) * L2E);
            const float p12 = exp2f((st[1][2] - m_run) * L2E);
            const float p13 = exp2f((st[1][3] - m_run) * L2E);
            float rs = p00 + p01 + p02 + p03 + p10 + p11 + p12 + p13;
            rs += __shfl_xor(rs, 16);
            rs += __shfl_xor(rs, 32);
            l_run += rs;

            uint c0, c1, c2, c3;
            asm("v_cvt_pk_bf16_f32 %0, %1, %2" : "=v"(c0) : "v"(p00), "v"(p01));
            asm("v_cvt_pk_bf16_f32 %0, %1, %2" : "=v"(c1) : "v"(p02), "v"(p03));
            asm("v_cvt_pk_bf16_f32 %0, %1, %2" : "=v"(c2) : "v"(p10), "v"(p11));
            asm("v_cvt_pk_bf16_f32 %0, %1, %2" : "=v"(c3) : "v"(p12), "v"(p13));
            // P octet layout: addr = (k>>4)*1024 + ((k>>3)&1)*512 + q_local*16 + (k&7)*2
            const int wbase = (h >> 1) * 512 + (h & 1) * 8 + (u * 16 + lq) * 16;
            *(uint*)(Pp + wbase)            = c0;   // g=0, k = h*4+0,1
            *(uint*)(Pp + wbase + 4)        = c1;   // g=0, k = h*4+2,3
            *(uint*)(Pp + 1024 + wbase)     = c2;   // g=1
            *(uint*)(Pp + 1024 + wbase + 4) = c3;
            if (h == 0)    *(float*)(Pf + (u * 16 + lq) * 4) = f_val;
            if (lane == 0) *(uint*)(Pf + 128 + u * 4) = anyneed ? 1u : 0u;
        }

        asm volatile("s_waitcnt lgkmcnt(0)" ::: "memory");
        __builtin_amdgcn_sched_barrier(0);
        __builtin_amdgcn_s_barrier();   // [#2] pair P/f visible; prefetch still in flight

        if (active) {
            // ---- apply pair rescale factors to acc (only when some wave rescaled) ----
            const uint2 fl = *(const uint2*)(Pf + 128);
            if (fl.x | fl.y) {
                f32x4 fr[4];
                #pragma unroll
                for (int i = 0; i < 4; ++i)
                    fr[i] = *(const f32x4*)(Pf + i * 32 + hh * 16);
                #pragma unroll
                for (int dt = 0; dt < 8; ++dt)
                    #pragma unroll
                    for (int rg = 0; rg < 16; ++rg)
                        acc[dt][rg] *= fr[rg >> 2][rg & 3];
            }

            // ---- O += P x V  (32x32x16, pair's 32 q x my 256-d half) ----
            bf16x8 pa0 = *(const bf16x8*)(Pp + hh * 512 + l31 * 16);          // k 0..15
            bf16x8 pa1 = *(const bf16x8*)(Pp + 1024 + hh * 512 + l31 * 16);   // k 16..31
            __builtin_amdgcn_s_setprio(1);
            #pragma unroll
            for (int dt = 0; dt < 8; ++dt) {
                const int vb = (u * 8 + dt) * 2048 + hh * 512 + l31 * 16;
                bf16x8 v0 = *(const bf16x8*)(Vsh + vb);
                bf16x8 v1 = *(const bf16x8*)(Vsh + vb + 1024);
                acc[dt] = __builtin_amdgcn_mfma_f32_32x32x16_bf16(pa0, v0, acc[dt], 0, 0, 0);
                acc[dt] = __builtin_amdgcn_mfma_f32_32x32x16_bf16(pa1, v1, acc[dt], 0, 0, 0);
            }
            __builtin_amdgcn_s_setprio(0);
        }
        __builtin_amdgcn_s_barrier();   // [#3] buffer free for next STAGE
        cur ^= 1;
    }

    // ---- epilogue: exchange l via pair table, normalize, store ----
    if (h == 0) *(float*)(Pf + (u * 16 + lq) * 4) = l_run;
    asm volatile("s_waitcnt lgkmcnt(0)" ::: "memory");
    __builtin_amdgcn_s_barrier();
    f32x4 iv[4];
    #pragma unroll
    for (int i = 0; i < 4; ++i) {
        f32x4 lv = *(const f32x4*)(Pf + i * 32 + hh * 16);
        iv[i][0] = 1.0f / lv[0]; iv[i][1] = 1.0f / lv[1];
        iv[i][2] = 1.0f / lv[2]; iv[i][3] = 1.0f / lv[3];
    }
    #pragma unroll
    for (int dt = 0; dt < 8; ++dt) {
        const int colb = u * 256 + dt * 32 + l31;
        #pragma unroll
        for (int rg = 0; rg < 16; ++rg) {
            const int row = pairbase + (rg & 3) + 8 * (rg >> 2) + 4 * hh;
            Op[(size_t)row * D_ + colb] = acc[dt][rg] * iv[rg >> 2][rg & 3];
        }
    }
}

// ---------------- fallback (no-ws path, reg-staged; unchanged) ----------------
#define FB_LDS (32768 + 32768 + 4 * 1024)
__global__ __launch_bounds__(256, 2) void gats_attn_fb(
    const float* __restrict__ Qg, const float* __restrict__ Kg,
    const float* __restrict__ Vg, float* __restrict__ Og)
{
    extern __shared__ char smem[];
    char* Ksh = smem;
    char* Vsh = smem + 32768;
    const int tid  = threadIdx.x;
    const int lane = tid & 63;
    const int wv   = tid >> 6;
    char* Psh = smem + 65536 + wv * 1024;
    const int bid = blockIdx.x;
    const int wh  = bid & 7;
    const int r2  = bid >> 3;
    const int w   = wh * 2 + (r2 & 1);
    const int b   = (r2 >> 1) & 3;
    const int y   = r2 >> 3;
    const int qbase  = w * WSZ + y * 64;
    const int wqbase = qbase + wv * 16;
    const size_t boff = (size_t)b * S_ * D_;
    const float* Qp = Qg + boff; const float* Kp = Kg + boff;
    const float* Vp = Vg + boff; float* Op = Og + boff;
    const float scale = 0.044194173824159216f;
    const float L2E   = 1.44269504088896f;
    bf16x8 qf[16];
    {
        const int qrow = wqbase + (lane & 15);
        const float* qsrc = Qp + (size_t)qrow * D_ + ((lane >> 4) * 8);
        #pragma unroll
        for (int c = 0; c < 16; ++c) {
            float4 a0 = *(const float4*)(qsrc + c * 32);
            float4 a1 = *(const float4*)(qsrc + c * 32 + 4);
            bf16x8 q;
            q[0] = (__bf16)(a0.x * scale); q[1] = (__bf16)(a0.y * scale);
            q[2] = (__bf16)(a0.z * scale); q[3] = (__bf16)(a0.w * scale);
            q[4] = (__bf16)(a1.x * scale); q[5] = (__bf16)(a1.y * scale);
            q[6] = (__bf16)(a1.z * scale); q[7] = (__bf16)(a1.w * scale);
            qf[c] = q;
        }
    }
    f32x4 acc[32];
    #pragma unroll
    for (int i = 0; i < 32; ++i) acc[i] = (f32x4){0.f, 0.f, 0.f, 0.f};
    float m_r[4], l_r[4];
    #pragma unroll
    for (int r = 0; r < 4; ++r) { m_r[r] = -1e30f; l_r[r] = 0.f; }
    const int kstart = (w == 0) ? 0 : (w - 1) * WSZ;
    const int ktend  = qbase + 64;
    for (int kt = kstart; kt < ktend; kt += 32) {
        __syncthreads();
        #pragma unroll
        for (int s = 0; s < 8; ++s) {
            const int row = s * 4 + wv;
            const int dof = lane * 8;
            const float4* src = (const float4*)(Kp + (size_t)(kt + row) * D_ + dof);
            float4 a0 = src[0], a1 = src[1];
            bf16x8 kv;
            kv[0] = (__bf16)a0.x; kv[1] = (__bf16)a0.y; kv[2] = (__bf16)a0.z; kv[3] = (__bf16)a0.w;
            kv[4] = (__bf16)a1.x; kv[5] = (__bf16)a1.y; kv[6] = (__bf16)a1.z; kv[7] = (__bf16)a1.w;
            const int byte = row * 1024 + ((dof * 2) ^ ((row & 7) << 4));
            *(bf16x8*)(Ksh + byte) = kv;
        }
        #pragma unroll
        for (int hh2 = 0; hh2 < 2; ++hh2) {
            const int d = tid + hh2 * 256;
            #pragma unroll
            for (int it = 0; it < 4; ++it) {
                float vvv[8];
                #pragma unroll
                for (int j = 0; j < 8; ++j)
                    vvv[j] = Vp[(size_t)(kt + it * 8 + j) * D_ + d];
                bf16x8 vb;
                #pragma unroll
                for (int j = 0; j < 8; ++j) vb[j] = (__bf16)vvv[j];
                const int byte = d * 64 + ((it * 16) ^ (((d >> 1) & 3) << 4));
                *(bf16x8*)(Vsh + byte) = vb;
            }
        }
        __syncthreads();
        if (kt > wqbase + 15) continue;
        f32x4 sacc[2];
        #pragma unroll
        for (int g = 0; g < 2; ++g) {
            f32x4 s = (f32x4){0.f, 0.f, 0.f, 0.f};
            const int keyrow = g * 16 + (lane & 15);
            #pragma unroll
            for (int c = 0; c < 16; ++c) {
                const int byte = keyrow * 1024 +
                                 ((c * 64 + (lane >> 4) * 16) ^ ((keyrow & 7) << 4));
                bf16x8 kf = *(const bf16x8*)(Ksh + byte);
                s = __builtin_amdgcn_mfma_f32_16x16x32_bf16(qf[c], kf, s, 0, 0, 0);
            }
            sacc[g] = s;
        }
        #pragma unroll
        for (int g = 0; g < 2; ++g) {
            if (kt + g * 16 + 15 > wqbase) {
                const int kg = kt + g * 16 + (lane & 15);
                #pragma unroll
                for (int r = 0; r < 4; ++r) {
                    const int qrow = wqbase + (lane >> 4) * 4 + r;
                    if (kg > qrow) sacc[g][r] = -1e30f;
                }
            }
        }
        float tmax[4];
        #pragma unroll
        for (int r = 0; r < 4; ++r) {
            float v = fmaxf(sacc[0][r], sacc[1][r]);
            #pragma unroll
            for (int off = 8; off >= 1; off >>= 1)
                v = fmaxf(v, __shfl_xor(v, off));
            tmax[r] = v;
        }
        bool need = false;
        #pragma unroll
        for (int r = 0; r < 4; ++r) need |= (tmax[r] > m_r[r] + 8.f);
        if (__any(need)) {
            #pragma unroll
            for (int r = 0; r < 4; ++r) {
                const float mnew = fmaxf(m_r[r], tmax[r]);
                const float f = exp2f((m_r[r] - mnew) * L2E);
                m_r[r] = mnew; l_r[r] *= f;
                #pragma unroll
                for (int dc = 0; dc < 32; ++dc) acc[dc][r] *= f;
            }
        }
        float rsum[4] = {0.f, 0.f, 0.f, 0.f};
        #pragma unroll
        for (int g = 0; g < 2; ++g) {
            #pragma unroll
            for (int r = 0; r < 4; ++r) {
                const float p = exp2f((sacc[g][r] - m_r[r]) * L2E);
                rsum[r] += p;
                const int prow = (lane >> 4) * 4 + r;
                const int byte = prow * 64 +
                                 ((g * 32 + (lane & 15) * 2) ^ (((prow >> 1) & 3) << 4));
                *(__bf16*)(Psh + byte) = (__bf16)p;
            }
        }
        #pragma unroll
        for (int r = 0; r < 4; ++r) {
            float v = rsum[r];
            #pragma unroll
            for (int off = 8; off >= 1; off >>= 1)
                v += __shfl_xor(v, off);
            l_r[r] += v;
        }
        {
            const int prow  = lane & 15;
            const int pbyte = prow * 64 +
                              (((lane >> 4) * 16) ^ (((prow >> 1) & 3) << 4));
            bf16x8 pa = *(const bf16x8*)(Psh + pbyte);
            #pragma unroll
            for (int dc = 0; dc < 32; ++dc) {
                const int d = dc * 16 + (lane & 15);
                const int vbyte = d * 64 +
                                  (((lane >> 4) * 16) ^ (((d >> 1) & 3) << 4));
                bf16x8 vf = *(const bf16x8*)(Vsh + vbyte);
                acc[dc] = __builtin_amdgcn_mfma_f32_16x16x32_bf16(pa, vf, acc[dc], 0, 0, 0);
            }
        }
    }
    float inv[4];
    #pragma unroll
    for (int r = 0; r < 4; ++r) inv[r] = 1.0f / l_r[r];
    #pragma unroll
    for (int dc = 0; dc < 32; ++dc) {
        #pragma unroll
        for (int r = 0; r < 4; ++r) {
            const int row = wqbase + (lane >> 4) * 4 + r;
            const int col = dc * 16 + (lane & 15);
            Op[(size_t)row * D_ + col] = acc[dc][r] * inv[r];
        }
    }
}

extern "C" void kernel_launch(void* const* d_in, const int* in_sizes, int n_in,
                              void* d_out, int out_size, void* d_ws, size_t ws_size,
                              hipStream_t stream) {
    const float* q = (const float*)d_in[0];   // text
    const float* k = (const float*)d_in[1];   // audio
    const float* v = (const float*)d_in[2];   // video
    float* o = (float*)d_out;

    const size_t elems = (size_t)4 * S_ * D_ * 4;   // 16,777,216 per tensor
    const size_t need  = elems * 2 * 2;             // K bf16 + Vt bf16 = 64MB
    if (ws_size >= need) {
        char* kb = (char*)d_ws;
        char* vt = (char*)d_ws + elems * 2;
        cvt_k<<<dim3(8192), dim3(256), 0, stream>>>(k, (ushort*)kb);
        tr_v <<<dim3(4096), dim3(256), 0, stream>>>(v, vt);
        hipFuncSetAttribute((const void*)gats_attn,
                            hipFuncAttributeMaxDynamicSharedMemorySize, ATT_LDS);
        gats_attn<<<dim3(256), dim3(ATT_THREADS), ATT_LDS, stream>>>(q, kb, vt, o);
    } else {
        hipFuncSetAttribute((const void*)gats_attn_fb,
                            hipFuncAttributeMaxDynamicSharedMemorySize, FB_LDS);
        gats_attn_fb<<<dim3(512), dim3(256), FB_LDS, stream>>>(q, k, v, o);
    }
}